// Round 3
// baseline (611.643 us; speedup 1.0000x reference)
//
#include <hip/hip_runtime.h>
#include <hip/hip_bf16.h>
#include <stdint.h>

// Problem constants
#define B_   2
#define S_   1024
#define HS_  1024
#define H_   16
#define D_   64
#define V_   1025   // vocab = 2*512+1
#define VP_  1056   // vocab padded to multiple of 32
#define BH_  32     // B_*H_
#define RTS_S 1072  // bf16 Rtile row stride (shorts), k_score
#define RTS3_ 1060  // f32 hist row stride (floats), k_rel; 1060*4 % 16 == 0

typedef __attribute__((ext_vector_type(8))) short  short8;
typedef __attribute__((ext_vector_type(4))) short  short4v;
typedef __attribute__((ext_vector_type(4))) float  floatx4;
typedef __attribute__((ext_vector_type(4))) int    intx4;
typedef __bf16 bf16x8 __attribute__((ext_vector_type(8)));

// f32 -> bf16 (RNE), bit pattern as short
__device__ inline short f2b(float f) {
  union { float f; uint32_t u; } c; c.f = f;
  uint32_t u = c.u;
  uint32_t r = (u + 0x7fffu + ((u >> 16) & 1u)) >> 16;
  return (short)r;
}
__device__ inline float b2f(short s) {
  union { uint32_t u; float f; } c; c.u = ((uint32_t)(uint16_t)s) << 16;
  return c.f;
}
// load 8 f32 (32B) and convert to bf16x8 (as short8)
__device__ inline short8 cvt8(const float* p) {
  const floatx4* p4 = reinterpret_cast<const floatx4*>(p);
  floatx4 x = p4[0], y = p4[1];
  short8 r;
  r[0]=f2b(x[0]); r[1]=f2b(x[1]); r[2]=f2b(x[2]); r[3]=f2b(x[3]);
  r[4]=f2b(y[0]); r[5]=f2b(y[1]); r[6]=f2b(y[2]); r[7]=f2b(y[3]);
  return r;
}
__device__ inline short8 load_s8(const short* p) {
  return *reinterpret_cast<const short8*>(p);
}
__device__ inline floatx4 mfma16(short8 a, short8 b, floatx4 c) {
  return __builtin_amdgcn_mfma_f32_16x16x32_bf16(
      __builtin_bit_cast(bf16x8, a), __builtin_bit_cast(bf16x8, b), c, 0, 0, 0);
}

// ---------------------------------------------------------------------------
// K0: prep embeddings:
//   rveT[d][p] = rve[p][d] bf16, zero-padded p in [V_,VP_)
//   rkeB[p][d] = rke[p][d] bf16
__global__ __launch_bounds__(256) void k_prep(const float* __restrict__ rve,
                                              const float* __restrict__ rke,
                                              short* __restrict__ rveT,
                                              short* __restrict__ rkeB) {
  int idx = blockIdx.x * 256 + threadIdx.x;
  if (idx < D_ * VP_) {
    int d = idx / VP_, p = idx % VP_;
    float v = (p < V_) ? rve[p * D_ + d] : 0.f;
    rveT[d * VP_ + p] = f2b(v);
  } else {
    int j = idx - D_ * VP_;
    if (j < V_ * D_) rkeB[j] = f2b(rke[j]);
  }
}

// ---------------------------------------------------------------------------
// K1: projections. which=0: qh = q@Wq^T+bq (bf16, (B*S,HS))
//                  which=1: kh          (bf16, (B*S,HS))
//                  which=2: vhT[b][h][d][s]  (bf16)
__global__ __launch_bounds__(256) void k_proj(
    const float* __restrict__ qi, const float* __restrict__ ki, const float* __restrict__ vi,
    const float* __restrict__ Wq, const float* __restrict__ bq,
    const float* __restrict__ Wk, const float* __restrict__ bk,
    const float* __restrict__ Wv, const float* __restrict__ bv,
    short* __restrict__ qh, short* __restrict__ kh, short* __restrict__ vhT) {
  int which = blockIdx.z;
  const float* X = which == 0 ? qi : which == 1 ? ki : vi;
  const float* W = which == 0 ? Wq : which == 1 ? Wk : Wv;
  const float* bias = which == 0 ? bq : which == 1 ? bk : bv;
  int m0 = blockIdx.y * 64, n0 = blockIdx.x * 64;
  int tid = threadIdx.x, wave = tid >> 6, lane = tid & 63;
  int qd = lane >> 4, c16 = lane & 15;
  __shared__ short Wl[64][40];   // 64 n-rows x 32 k, pad to 40 shorts
  floatx4 acc[4] = {};
  int mrow = m0 + wave * 16 + c16;
  const float* arow = X + (size_t)mrow * HS_ + qd * 8;
  int sn = tid >> 2, sk = (tid & 3) * 8;
  const float* wrow = W + (size_t)(n0 + sn) * HS_ + sk;
  for (int kc = 0; kc < HS_; kc += 32) {
    short8 wsv = cvt8(wrow + kc);
    *reinterpret_cast<short8*>(&Wl[sn][sk]) = wsv;
    __syncthreads();
    short8 a = cvt8(arow + kc);
#pragma unroll
    for (int nt = 0; nt < 4; nt++) {
      short8 b = *reinterpret_cast<const short8*>(&Wl[nt * 16 + c16][qd * 8]);
      acc[nt] = mfma16(a, b, acc[nt]);
    }
    __syncthreads();
  }
#pragma unroll
  for (int nt = 0; nt < 4; nt++) {
    int col = n0 + nt * 16 + c16;
    float bsum = bias[col];
    if (which < 2) {
      short* dst = which == 0 ? qh : kh;
#pragma unroll
      for (int r = 0; r < 4; r++) {
        int row = m0 + wave * 16 + qd * 4 + r;
        dst[(size_t)row * HS_ + col] = f2b(acc[nt][r] + bsum);
      }
    } else {
      int h = col >> 6, d = col & 63;
      int srow = m0 + wave * 16 + qd * 4;   // 4 consecutive s values
      int bb = srow >> 10, s = srow & 1023;
      short4v pk;
#pragma unroll
      for (int r = 0; r < 4; r++) pk[r] = f2b(acc[nt][r] + bsum);
      *reinterpret_cast<short4v*>(&vhT[(((size_t)(bb * H_ + h)) * D_ + d) * S_ + s]) = pk;
    }
  }
}

// ---------------------------------------------------------------------------
// K3a: scores for one (b,h, 16-q tile):
//  P0: Rt[16][1072] = qh_tile @ rkeB^T  (LDS, bf16  -> 34.3 KB, 4 blocks/CU)
//  P1: logits (registers) = qh.kh^T + Rt[rp gather]
//  P2: softmax in registers (shfl + tiny LDS cross-wave reduce)
//  P3: write weights (global)
__global__ __launch_bounds__(256, 4) void k_score(
    const short* __restrict__ qh, const short* __restrict__ kh,
    const short* __restrict__ rkeB, const int* __restrict__ rp,
    float* __restrict__ weights) {
  int bh = blockIdx.y;
  int b = bh >> 4, h = bh & 15;
  int q0 = blockIdx.x * 16;
  int tid = threadIdx.x, wave = tid >> 6, lane = tid & 63;
  int qd = lane >> 4, c16 = lane & 15;
  __shared__ short Rt[16 * RTS_S];   // bf16 Rtile
  __shared__ float redA[4 * 16];
  __shared__ float redB[4 * 16];

  // A-fragments for the 16 q rows (shared by P0 and P1)
  const short* aptr = qh + ((size_t)b * S_ + q0 + c16) * HS_ + h * 64 + qd * 8;
  short8 a0 = load_s8(aptr), a1 = load_s8(aptr + 32);

  // ---- P0: Rt = qh_tile(16x64) @ rkeB^T(64x1056) -> LDS bf16
  for (int nt = wave; nt < VP_ / 16; nt += 4) {
    int p = nt * 16 + c16;
    short8 b0 = {}, b1 = {};
    if (p < V_) {
      b0 = load_s8(rkeB + (size_t)p * D_ + qd * 8);
      b1 = load_s8(rkeB + (size_t)p * D_ + 32 + qd * 8);
    }
    floatx4 acc = {};
    acc = mfma16(a0, b0, acc);
    acc = mfma16(a1, b1, acc);
#pragma unroll
    for (int r = 0; r < 4; r++) Rt[(qd * 4 + r) * RTS_S + p] = f2b(acc[r]);
  }
  __syncthreads();

  // ---- P1: logits in registers
  floatx4 acc[16];
  const int* rpq = rp + (size_t)q0 * S_;
#pragma unroll
  for (int it = 0; it < 16; it++) {
    int col = wave * 256 + it * 16 + c16;
    const short* bptr = kh + ((size_t)b * S_ + col) * HS_ + h * 64 + qd * 8;
    floatx4 a = {};
    a = mfma16(a0, load_s8(bptr), a);
    a = mfma16(a1, load_s8(bptr + 32), a);
#pragma unroll
    for (int r = 0; r < 4; r++) {
      int row = qd * 4 + r;
      int p = rpq[(size_t)row * S_ + col];
      a[r] += b2f(Rt[row * RTS_S + p]);
    }
    acc[it] = a;
  }

  // ---- P2: softmax over registers
  float mx[4], inv[4];
#pragma unroll
  for (int r = 0; r < 4; r++) {
    float m = -1e30f;
#pragma unroll
    for (int it = 0; it < 16; it++) m = fmaxf(m, acc[it][r]);
#pragma unroll
    for (int off = 1; off < 16; off <<= 1) m = fmaxf(m, __shfl_xor(m, off));
    mx[r] = m;
    if (c16 == 0) redA[wave * 16 + qd * 4 + r] = m;
  }
  __syncthreads();
#pragma unroll
  for (int r = 0; r < 4; r++) {
    int row = qd * 4 + r;
    float m = fmaxf(fmaxf(redA[row], redA[16 + row]),
                    fmaxf(redA[32 + row], redA[48 + row]));
    mx[r] = m;
  }
  float sm[4] = {0.f, 0.f, 0.f, 0.f};
#pragma unroll
  for (int it = 0; it < 16; it++) {
#pragma unroll
    for (int r = 0; r < 4; r++) {
      float e = __expf(acc[it][r] - mx[r]);
      acc[it][r] = e;
      sm[r] += e;
    }
  }
#pragma unroll
  for (int r = 0; r < 4; r++) {
#pragma unroll
    for (int off = 1; off < 16; off <<= 1) sm[r] += __shfl_xor(sm[r], off);
    if (c16 == 0) redB[wave * 16 + qd * 4 + r] = sm[r];
  }
  __syncthreads();
#pragma unroll
  for (int r = 0; r < 4; r++) {
    int row = qd * 4 + r;
    inv[r] = 1.f / (redB[row] + redB[16 + row] + redB[32 + row] + redB[48 + row]);
  }

  // ---- P3: write weights
  float* wout = weights + (size_t)bh * S_ * S_ + (size_t)q0 * S_;
#pragma unroll
  for (int it = 0; it < 16; it++) {
    int col = wave * 256 + it * 16 + c16;
#pragma unroll
    for (int r = 0; r < 4; r++) {
      wout[(size_t)(qd * 4 + r) * S_ + col] = acc[it][r] * inv[r];
    }
  }
}

// ---------------------------------------------------------------------------
// K3b: relative-value context for one (bh, 8-q tile):
//   hist[8][1060] f32 in LDS (33.9 KB -> 4 blocks/CU)
//   scatter: wave w owns k-quarter; lane: row=lane>>3, 8 k per iter, 4 iters
//   hist GEMM: accr(8q x 16d per wave) = hist @ rveT  (MFMA, A rows 8..15 = 0)
__global__ __launch_bounds__(256, 4) void k_rel(
    const float* __restrict__ weights, const int* __restrict__ rp,
    const short* __restrict__ rveT, float* __restrict__ ctx_rel) {
  int bh = blockIdx.y;
  int b = bh >> 4, h = bh & 15;
  int q0 = blockIdx.x * 8;
  int tid = threadIdx.x, wave = tid >> 6, lane = tid & 63;
  int qd = lane >> 4, c16 = lane & 15;
  __shared__ float hist[8 * RTS3_];   // 33.9 KB

  // zero hist (8*1060/4 = 2120 float4)
  {
    floatx4 z = {};
    floatx4* h4 = reinterpret_cast<floatx4*>(hist);
    for (int i = tid; i < 8 * RTS3_ / 4; i += 256) h4[i] = z;
  }
  __syncthreads();

  // scatter: wave owns k in [wave*256, wave*256+256)
  {
    int r = lane >> 3;            // q row 0..7
    int kb = (lane & 7) * 8;      // 0..56
    const float* wr = weights + ((size_t)bh * S_ + q0 + r) * S_ + wave * 256 + kb;
    const int*   pr = rp + (size_t)(q0 + r) * S_ + wave * 256 + kb;
    float* hrow = hist + r * RTS3_;
#pragma unroll
    for (int it = 0; it < 4; it++) {
      const floatx4* w4 = reinterpret_cast<const floatx4*>(wr + it * 64);
      const intx4*   p4 = reinterpret_cast<const intx4*>(pr + it * 64);
      floatx4 x = w4[0], y = w4[1];
      intx4 pA = p4[0], pB = p4[1];
      atomicAdd(&hrow[pA[0]], x[0]);
      atomicAdd(&hrow[pA[1]], x[1]);
      atomicAdd(&hrow[pA[2]], x[2]);
      atomicAdd(&hrow[pA[3]], x[3]);
      atomicAdd(&hrow[pB[0]], y[0]);
      atomicAdd(&hrow[pB[1]], y[1]);
      atomicAdd(&hrow[pB[2]], y[2]);
      atomicAdd(&hrow[pB[3]], y[3]);
    }
  }
  __syncthreads();

  // hist GEMM: per wave 16 d cols (d = wave*16 + c16); A rows 8..15 zero
  floatx4 accr = {};
  const short* brv = rveT + (size_t)(wave * 16 + c16) * VP_;
  const float* hrd = hist + c16 * RTS3_;   // valid only for c16 < 8
  for (int kc = 0; kc < VP_; kc += 32) {
    short8 a = {};
    if (c16 < 8) a = cvt8(hrd + kc + qd * 8);
    short8 bfr = load_s8(brv + kc + qd * 8);
    accr = mfma16(a, bfr, accr);
  }
  // C rows qd*4+r ; rows 0..7 valid (qd<2)
  if (qd < 2) {
    float* cr = ctx_rel + ((size_t)b * S_ + q0 + qd * 4) * HS_ + h * 64 + wave * 16 + c16;
#pragma unroll
    for (int r = 0; r < 4; r++) {
      cr[(size_t)r * HS_] = accr[r];
    }
  }
}

// ---------------------------------------------------------------------------
// K4: content GEMM + add: ctx = bf16(weights @ vhT + ctx_rel)
//   32q x 64d tile per block; 4 waves = (q-half, d-half); 4 blocks/CU
__global__ __launch_bounds__(256, 4) void k_ctx2(
    const float* __restrict__ weights, const short* __restrict__ vhT,
    const float* __restrict__ ctx_rel, short* __restrict__ ctx) {
  int bh = blockIdx.y;
  int b = bh >> 4, h = bh & 15;
  int q0 = blockIdx.x * 32;
  int tid = threadIdx.x, wave = tid >> 6, lane = tid & 63;
  int qd = lane >> 4, c16 = lane & 15;
  int mt = wave >> 1;         // q-half (0/1)
  int dh = wave & 1;          // d-half (0/1)
  __shared__ short Vl[64][40];
  floatx4 acc[2] = {};
  const float* arow = weights + ((size_t)bh * S_ + q0 + mt * 16 + c16) * S_ + qd * 8;
  int sd = tid >> 2, sk = (tid & 3) * 8;
  const short* vrow = vhT + ((size_t)bh * D_ + sd) * S_ + sk;
  for (int kc = 0; kc < S_; kc += 32) {
    *reinterpret_cast<short8*>(&Vl[sd][sk]) = load_s8(vrow + kc);
    __syncthreads();
    short8 a = cvt8(arow + kc);
#pragma unroll
    for (int nt = 0; nt < 2; nt++) {
      short8 bfr = *reinterpret_cast<const short8*>(&Vl[dh * 32 + nt * 16 + c16][qd * 8]);
      acc[nt] = mfma16(a, bfr, acc[nt]);
    }
    __syncthreads();
  }
#pragma unroll
  for (int nt = 0; nt < 2; nt++) {
    int d = dh * 32 + nt * 16 + c16;
#pragma unroll
    for (int r = 0; r < 4; r++) {
      int q = q0 + mt * 16 + qd * 4 + r;
      size_t off = ((size_t)b * S_ + q) * HS_ + h * 64 + d;
      ctx[off] = f2b(acc[nt][r] + ctx_rel[off]);
    }
  }
}

// ---------------------------------------------------------------------------
// K5: out0 = ctx @ Wo^T + bo   (f32)
__global__ __launch_bounds__(256) void k_oproj(
    const short* __restrict__ ctx, const float* __restrict__ Wo,
    const float* __restrict__ bo, float* __restrict__ out0) {
  int m0 = blockIdx.y * 64, n0 = blockIdx.x * 64;
  int tid = threadIdx.x, wave = tid >> 6, lane = tid & 63;
  int qd = lane >> 4, c16 = lane & 15;
  __shared__ short Wl[64][40];
  floatx4 acc[4] = {};
  const short* arow = ctx + (size_t)(m0 + wave * 16 + c16) * HS_ + qd * 8;
  int sn = tid >> 2, sk = (tid & 3) * 8;
  const float* wrow = Wo + (size_t)(n0 + sn) * HS_ + sk;
  for (int kc = 0; kc < HS_; kc += 32) {
    short8 wsv = cvt8(wrow + kc);
    *reinterpret_cast<short8*>(&Wl[sn][sk]) = wsv;
    __syncthreads();
    short8 a = load_s8(arow + kc);
#pragma unroll
    for (int nt = 0; nt < 4; nt++) {
      short8 b = *reinterpret_cast<const short8*>(&Wl[nt * 16 + c16][qd * 8]);
      acc[nt] = mfma16(a, b, acc[nt]);
    }
    __syncthreads();
  }
#pragma unroll
  for (int nt = 0; nt < 4; nt++) {
    int col = n0 + nt * 16 + c16;
    float bsum = bo[col];
#pragma unroll
    for (int r = 0; r < 4; r++) {
      int row = m0 + wave * 16 + qd * 4 + r;
      out0[(size_t)row * HS_ + col] = acc[nt][r] + bsum;
    }
  }
}

// ---------------------------------------------------------------------------
// K6: out = LayerNorm(out0 + residual) * g + b
__global__ __launch_bounds__(256) void k_ln(
    const float* __restrict__ out0, const float* __restrict__ resid,
    const float* __restrict__ g, const float* __restrict__ bb,
    float* __restrict__ out) {
  int row = blockIdx.x;
  int tid = threadIdx.x, wave = tid >> 6, lane = tid & 63;
  const floatx4* x4 = reinterpret_cast<const floatx4*>(out0 + (size_t)row * HS_);
  const floatx4* r4 = reinterpret_cast<const floatx4*>(resid + (size_t)row * HS_);
  floatx4 x = x4[tid] + r4[tid];
  float s = x[0] + x[1] + x[2] + x[3];
  float ss = x[0]*x[0] + x[1]*x[1] + x[2]*x[2] + x[3]*x[3];
  __shared__ float red[8];
#pragma unroll
  for (int off = 32; off > 0; off >>= 1) {
    s += __shfl_xor(s, off);
    ss += __shfl_xor(ss, off);
  }
  if (lane == 0) { red[wave] = s; red[wave + 4] = ss; }
  __syncthreads();
  s = red[0] + red[1] + red[2] + red[3];
  ss = red[4] + red[5] + red[6] + red[7];
  float mu = s * (1.f / 1024.f);
  float var = ss * (1.f / 1024.f) - mu * mu;
  float rs = rsqrtf(var + 1e-5f);
  int c = tid * 4;
  floatx4 gg = *reinterpret_cast<const floatx4*>(g + c);
  floatx4 bv = *reinterpret_cast<const floatx4*>(bb + c);
  floatx4 y = (x - mu) * rs * gg + bv;
  reinterpret_cast<floatx4*>(out + (size_t)row * HS_)[tid] = y;
}

// ---------------------------------------------------------------------------
extern "C" void kernel_launch(void* const* d_in, const int* in_sizes, int n_in,
                              void* d_out, int out_size, void* d_ws, size_t ws_size,
                              hipStream_t stream) {
  const float* q   = (const float*)d_in[0];
  const float* k   = (const float*)d_in[1];
  const float* v   = (const float*)d_in[2];
  const int*   rp  = (const int*)d_in[3];
  const float* Wq  = (const float*)d_in[4];
  const float* bq  = (const float*)d_in[5];
  const float* Wk  = (const float*)d_in[6];
  const float* bk  = (const float*)d_in[7];
  const float* Wv  = (const float*)d_in[8];
  const float* bv  = (const float*)d_in[9];
  const float* rke = (const float*)d_in[10];
  const float* rve = (const float*)d_in[11];
  const float* Wo  = (const float*)d_in[12];
  const float* bo  = (const float*)d_in[13];
  const float* lng = (const float*)d_in[14];
  const float* lnb = (const float*)d_in[15];

  float* out = (float*)d_out;                         // (B,S,HS) f32
  float* weights = out + (size_t)B_ * S_ * HS_;       // (B,H,S,S) f32

  // workspace layout (bytes) — offsets audited for non-overlap:
  //   qh      [ 0        ,  4194304)
  //   kh      [ 4194304  ,  8388608)
  //   vhT     [ 8388608  , 12582912)
  //   ctx     [12582912  , 16777216)
  //   rveT    [16777216  , 16912384)   D_*VP_*2  = 135168
  //   rkeB    [16912384  , 17043584)   V_*D_*2   = 131200
  //   ctx_rel [17043968  , 25432576)   8 MB (256-aligned, after rkeB end)
  //   out0    [25432576  , 33821184)   8 MB
  char* ws = (char*)d_ws;
  short* qh      = (short*)(ws);
  short* kh      = (short*)(ws + 4194304);
  short* vhT     = (short*)(ws + 8388608);
  short* ctx     = (short*)(ws + 12582912);
  short* rveT    = (short*)(ws + 16777216);
  short* rkeB    = (short*)(ws + 16912384);
  float* ctx_rel = (float*)(ws + 17043968);
  float* out0    = (float*)(ws + 25432576);

  k_prep  <<<dim3(521),        256, 0, stream>>>(rve, rke, rveT, rkeB);
  k_proj  <<<dim3(16, 32, 3),  256, 0, stream>>>(q, k, v, Wq, bq, Wk, bk, Wv, bv, qh, kh, vhT);
  k_score <<<dim3(64, 32),     256, 0, stream>>>(qh, kh, rkeB, rp, weights);
  k_rel   <<<dim3(128, 32),    256, 0, stream>>>(weights, rp, rveT, ctx_rel);
  k_ctx2  <<<dim3(32, 32),     256, 0, stream>>>(weights, vhT, ctx_rel, ctx);
  k_oproj <<<dim3(16, 32),     256, 0, stream>>>(ctx, Wo, bo, out0);
  k_ln    <<<dim3(2048),       256, 0, stream>>>(out0, q, lng, lnb, out);
}

// Round 4
// 447.719 us; speedup vs baseline: 1.3661x; 1.3661x over previous
//
#include <hip/hip_runtime.h>
#include <hip/hip_bf16.h>
#include <stdint.h>

// Problem constants
#define B_   2
#define S_   1024
#define HS_  1024
#define H_   16
#define D_   64
#define V_   1025   // vocab = 2*512+1
#define VP_  1056   // vocab padded to multiple of 32
#define BH_  32     // B_*H_
#define RTS_S 1072  // bf16 Rtile row stride (shorts), k_score
#define RVS_  66    // Rv tile row stride (shorts), k_relgemm: 33 dwords -> conflict-free cols

typedef __attribute__((ext_vector_type(8))) short  short8;
typedef __attribute__((ext_vector_type(4))) short  short4v;
typedef __attribute__((ext_vector_type(4))) float  floatx4;
typedef __attribute__((ext_vector_type(4))) int    intx4;
typedef __bf16 bf16x8 __attribute__((ext_vector_type(8)));

// f32 -> bf16 (RNE), bit pattern as short
__device__ inline short f2b(float f) {
  union { float f; uint32_t u; } c; c.f = f;
  uint32_t u = c.u;
  uint32_t r = (u + 0x7fffu + ((u >> 16) & 1u)) >> 16;
  return (short)r;
}
__device__ inline float b2f(short s) {
  union { uint32_t u; float f; } c; c.u = ((uint32_t)(uint16_t)s) << 16;
  return c.f;
}
// load 8 f32 (32B) and convert to bf16x8 (as short8)
__device__ inline short8 cvt8(const float* p) {
  const floatx4* p4 = reinterpret_cast<const floatx4*>(p);
  floatx4 x = p4[0], y = p4[1];
  short8 r;
  r[0]=f2b(x[0]); r[1]=f2b(x[1]); r[2]=f2b(x[2]); r[3]=f2b(x[3]);
  r[4]=f2b(y[0]); r[5]=f2b(y[1]); r[6]=f2b(y[2]); r[7]=f2b(y[3]);
  return r;
}
__device__ inline short8 load_s8(const short* p) {
  return *reinterpret_cast<const short8*>(p);
}
__device__ inline floatx4 mfma16(short8 a, short8 b, floatx4 c) {
  return __builtin_amdgcn_mfma_f32_16x16x32_bf16(
      __builtin_bit_cast(bf16x8, a), __builtin_bit_cast(bf16x8, b), c, 0, 0, 0);
}

// ---------------------------------------------------------------------------
// K0: prep embeddings (both p-major bf16):
//   rveB[p][d] = rve[p][d] bf16
//   rkeB[p][d] = rke[p][d] bf16
__global__ __launch_bounds__(256) void k_prep(const float* __restrict__ rve,
                                              const float* __restrict__ rke,
                                              short* __restrict__ rveB,
                                              short* __restrict__ rkeB) {
  int idx = blockIdx.x * 256 + threadIdx.x;
  if (idx < V_ * D_) {
    rveB[idx] = f2b(rve[idx]);
  } else {
    int j = idx - V_ * D_;
    if (j < V_ * D_) rkeB[j] = f2b(rke[j]);
  }
}

// ---------------------------------------------------------------------------
// K1: projections. which=0: qh = q@Wq^T+bq (bf16, (B*S,HS))
//                  which=1: kh          (bf16, (B*S,HS))
//                  which=2: vhT[b][h][d][s]  (bf16)
__global__ __launch_bounds__(256) void k_proj(
    const float* __restrict__ qi, const float* __restrict__ ki, const float* __restrict__ vi,
    const float* __restrict__ Wq, const float* __restrict__ bq,
    const float* __restrict__ Wk, const float* __restrict__ bk,
    const float* __restrict__ Wv, const float* __restrict__ bv,
    short* __restrict__ qh, short* __restrict__ kh, short* __restrict__ vhT) {
  int which = blockIdx.z;
  const float* X = which == 0 ? qi : which == 1 ? ki : vi;
  const float* W = which == 0 ? Wq : which == 1 ? Wk : Wv;
  const float* bias = which == 0 ? bq : which == 1 ? bk : bv;
  int m0 = blockIdx.y * 64, n0 = blockIdx.x * 64;
  int tid = threadIdx.x, wave = tid >> 6, lane = tid & 63;
  int qd = lane >> 4, c16 = lane & 15;
  __shared__ short Wl[64][40];   // 64 n-rows x 32 k, pad to 40 shorts
  floatx4 acc[4] = {};
  int mrow = m0 + wave * 16 + c16;
  const float* arow = X + (size_t)mrow * HS_ + qd * 8;
  int sn = tid >> 2, sk = (tid & 3) * 8;
  const float* wrow = W + (size_t)(n0 + sn) * HS_ + sk;
  for (int kc = 0; kc < HS_; kc += 32) {
    short8 wsv = cvt8(wrow + kc);
    *reinterpret_cast<short8*>(&Wl[sn][sk]) = wsv;
    __syncthreads();
    short8 a = cvt8(arow + kc);
#pragma unroll
    for (int nt = 0; nt < 4; nt++) {
      short8 b = *reinterpret_cast<const short8*>(&Wl[nt * 16 + c16][qd * 8]);
      acc[nt] = mfma16(a, b, acc[nt]);
    }
    __syncthreads();
  }
#pragma unroll
  for (int nt = 0; nt < 4; nt++) {
    int col = n0 + nt * 16 + c16;
    float bsum = bias[col];
    if (which < 2) {
      short* dst = which == 0 ? qh : kh;
#pragma unroll
      for (int r = 0; r < 4; r++) {
        int row = m0 + wave * 16 + qd * 4 + r;
        dst[(size_t)row * HS_ + col] = f2b(acc[nt][r] + bsum);
      }
    } else {
      int h = col >> 6, d = col & 63;
      int srow = m0 + wave * 16 + qd * 4;   // 4 consecutive s values
      int bb = srow >> 10, s = srow & 1023;
      short4v pk;
#pragma unroll
      for (int r = 0; r < 4; r++) pk[r] = f2b(acc[nt][r] + bsum);
      *reinterpret_cast<short4v*>(&vhT[(((size_t)(bb * H_ + h)) * D_ + d) * S_ + s]) = pk;
    }
  }
}

// ---------------------------------------------------------------------------
// K3a: scores for one (b,h, 16-q tile):
//  P0: Rt[16][1072] = qh_tile @ rkeB^T  (LDS, bf16  -> 34.3 KB, 4 blocks/CU)
//  P1: logits (registers) = qh.kh^T + Rt[rp gather]
//  P2: softmax in registers (shfl + tiny LDS cross-wave reduce)
//  P3: write weights (global)
__global__ __launch_bounds__(256, 4) void k_score(
    const short* __restrict__ qh, const short* __restrict__ kh,
    const short* __restrict__ rkeB, const int* __restrict__ rp,
    float* __restrict__ weights) {
  int bh = blockIdx.y;
  int b = bh >> 4, h = bh & 15;
  int q0 = blockIdx.x * 16;
  int tid = threadIdx.x, wave = tid >> 6, lane = tid & 63;
  int qd = lane >> 4, c16 = lane & 15;
  __shared__ short Rt[16 * RTS_S];   // bf16 Rtile
  __shared__ float redA[4 * 16];
  __shared__ float redB[4 * 16];

  // A-fragments for the 16 q rows (shared by P0 and P1)
  const short* aptr = qh + ((size_t)b * S_ + q0 + c16) * HS_ + h * 64 + qd * 8;
  short8 a0 = load_s8(aptr), a1 = load_s8(aptr + 32);

  // ---- P0: Rt = qh_tile(16x64) @ rkeB^T(64x1056) -> LDS bf16
  for (int nt = wave; nt < VP_ / 16; nt += 4) {
    int p = nt * 16 + c16;
    short8 b0 = {}, b1 = {};
    if (p < V_) {
      b0 = load_s8(rkeB + (size_t)p * D_ + qd * 8);
      b1 = load_s8(rkeB + (size_t)p * D_ + 32 + qd * 8);
    }
    floatx4 acc = {};
    acc = mfma16(a0, b0, acc);
    acc = mfma16(a1, b1, acc);
#pragma unroll
    for (int r = 0; r < 4; r++) Rt[(qd * 4 + r) * RTS_S + p] = f2b(acc[r]);
  }
  __syncthreads();

  // ---- P1: logits in registers
  floatx4 acc[16];
  const int* rpq = rp + (size_t)q0 * S_;
#pragma unroll
  for (int it = 0; it < 16; it++) {
    int col = wave * 256 + it * 16 + c16;
    const short* bptr = kh + ((size_t)b * S_ + col) * HS_ + h * 64 + qd * 8;
    floatx4 a = {};
    a = mfma16(a0, load_s8(bptr), a);
    a = mfma16(a1, load_s8(bptr + 32), a);
#pragma unroll
    for (int r = 0; r < 4; r++) {
      int row = qd * 4 + r;
      int p = rpq[(size_t)row * S_ + col];
      a[r] += b2f(Rt[row * RTS_S + p]);
    }
    acc[it] = a;
  }

  // ---- P2: softmax over registers
  float mx[4], inv[4];
#pragma unroll
  for (int r = 0; r < 4; r++) {
    float m = -1e30f;
#pragma unroll
    for (int it = 0; it < 16; it++) m = fmaxf(m, acc[it][r]);
#pragma unroll
    for (int off = 1; off < 16; off <<= 1) m = fmaxf(m, __shfl_xor(m, off));
    mx[r] = m;
    if (c16 == 0) redA[wave * 16 + qd * 4 + r] = m;
  }
  __syncthreads();
#pragma unroll
  for (int r = 0; r < 4; r++) {
    int row = qd * 4 + r;
    float m = fmaxf(fmaxf(redA[row], redA[16 + row]),
                    fmaxf(redA[32 + row], redA[48 + row]));
    mx[r] = m;
  }
  float sm[4] = {0.f, 0.f, 0.f, 0.f};
#pragma unroll
  for (int it = 0; it < 16; it++) {
#pragma unroll
    for (int r = 0; r < 4; r++) {
      float e = __expf(acc[it][r] - mx[r]);
      acc[it][r] = e;
      sm[r] += e;
    }
  }
#pragma unroll
  for (int r = 0; r < 4; r++) {
#pragma unroll
    for (int off = 1; off < 16; off <<= 1) sm[r] += __shfl_xor(sm[r], off);
    if (c16 == 0) redB[wave * 16 + qd * 4 + r] = sm[r];
  }
  __syncthreads();
#pragma unroll
  for (int r = 0; r < 4; r++) {
    int row = qd * 4 + r;
    inv[r] = 1.f / (redB[row] + redB[16 + row] + redB[32 + row] + redB[48 + row]);
  }

  // ---- P3: write weights
  float* wout = weights + (size_t)bh * S_ * S_ + (size_t)q0 * S_;
#pragma unroll
  for (int it = 0; it < 16; it++) {
    int col = wave * 256 + it * 16 + c16;
#pragma unroll
    for (int r = 0; r < 4; r++) {
      wout[(size_t)(qd * 4 + r) * S_ + col] = acc[it][r] * inv[r];
    }
  }
}

// ---------------------------------------------------------------------------
// K3b: relative-value context as a per-q GEMM (no histogram, no atomics):
//   for fixed q: C[32 bh][64 d] = sum_k w[bh,q,k] * rveB[rp[q,k]][d]
//   M=32 (2 MFMA M-tiles), K=1024 (32 steps of 32), N=64 (4 waves x 16 d)
//   A-tile: 32bh x 32k  f32->bf16, staged in LDS  (2 KB)
//   B-tile: 32k x 64d   gathered rows of rveB, staged in LDS (4.2 KB)
__global__ __launch_bounds__(256, 4) void k_relgemm(
    const float* __restrict__ weights, const int* __restrict__ rp,
    const short* __restrict__ rveB, float* __restrict__ ctx_rel) {
  int q = blockIdx.x;
  int tid = threadIdx.x, wave = tid >> 6, lane = tid & 63;
  int qd = lane >> 4, c16 = lane & 15;
  __shared__ int   rpl[S_];          // rp row for this q (4 KB)
  __shared__ short Wl[32][40];       // A-tile, pad 40
  __shared__ short Rv[32][RVS_];     // B-tile, stride 66 shorts (33 dwords)

  // stage rp row once (coalesced int4)
  {
    const intx4* r4 = reinterpret_cast<const intx4*>(rp + (size_t)q * S_);
    reinterpret_cast<intx4*>(rpl)[tid] = r4[tid];
  }
  __syncthreads();

  int sn = tid >> 3;             // 0..31: bh row (A) / k row (B)
  int sk = (tid & 7) * 4;        // A: 4 f32 per thread
  int part = tid & 7;            // B: 8 bf16 per thread
  const float* wbase = weights + ((size_t)sn * S_ + q) * S_;
  floatx4 acc0 = {}, acc1 = {};
  int d0 = wave * 16;

  for (int kc = 0; kc < S_; kc += 32) {
    // stage A: w[bh=sn][q][kc+sk .. +4] -> bf16
    {
      floatx4 wv = *reinterpret_cast<const floatx4*>(wbase + kc + sk);
      short4v pk;
      pk[0] = f2b(wv[0]); pk[1] = f2b(wv[1]);
      pk[2] = f2b(wv[2]); pk[3] = f2b(wv[3]);
      *reinterpret_cast<short4v*>(&Wl[sn][sk]) = pk;
    }
    // stage B: row sn of this k-chunk = rveB[rp[q,kc+sn]][:], 8 lanes/row
    {
      int p = rpl[kc + sn];
      *reinterpret_cast<short8*>(&Rv[sn][part * 8]) =
          load_s8(rveB + (size_t)p * D_ + part * 8);
    }
    __syncthreads();
    short8 a0 = *reinterpret_cast<const short8*>(&Wl[c16][qd * 8]);
    short8 a1 = *reinterpret_cast<const short8*>(&Wl[16 + c16][qd * 8]);
    short8 bfr;
#pragma unroll
    for (int j = 0; j < 8; j++) bfr[j] = Rv[qd * 8 + j][d0 + c16];
    acc0 = mfma16(a0, bfr, acc0);
    acc1 = mfma16(a1, bfr, acc1);
    __syncthreads();
  }

  // epilogue: C rows = bh = mt*16 + qd*4 + r ; cols = d0 + c16
  int dd = d0 + c16;
#pragma unroll
  for (int r = 0; r < 4; r++) {
    int bh0 = qd * 4 + r;        // b=0, h=bh0
    int bh1 = 16 + bh0;          // b=1, h=bh0
    ctx_rel[((size_t)0 * S_ + q) * HS_ + bh0 * 64 + dd] = acc0[r];
    ctx_rel[((size_t)1 * S_ + q) * HS_ + bh0 * 64 + dd] = acc1[r];
  }
}

// ---------------------------------------------------------------------------
// K4: content GEMM + add: ctx = bf16(weights @ vhT + ctx_rel)
//   32q x 64d tile per block; 4 waves = (q-half, d-half); 4 blocks/CU
__global__ __launch_bounds__(256, 4) void k_ctx2(
    const float* __restrict__ weights, const short* __restrict__ vhT,
    const float* __restrict__ ctx_rel, short* __restrict__ ctx) {
  int bh = blockIdx.y;
  int b = bh >> 4, h = bh & 15;
  int q0 = blockIdx.x * 32;
  int tid = threadIdx.x, wave = tid >> 6, lane = tid & 63;
  int qd = lane >> 4, c16 = lane & 15;
  int mt = wave >> 1;         // q-half (0/1)
  int dh = wave & 1;          // d-half (0/1)
  __shared__ short Vl[64][40];
  floatx4 acc[2] = {};
  const float* arow = weights + ((size_t)bh * S_ + q0 + mt * 16 + c16) * S_ + qd * 8;
  int sd = tid >> 2, sk = (tid & 3) * 8;
  const short* vrow = vhT + ((size_t)bh * D_ + sd) * S_ + sk;
  for (int kc = 0; kc < S_; kc += 32) {
    *reinterpret_cast<short8*>(&Vl[sd][sk]) = load_s8(vrow + kc);
    __syncthreads();
    short8 a = cvt8(arow + kc);
#pragma unroll
    for (int nt = 0; nt < 2; nt++) {
      short8 bfr = *reinterpret_cast<const short8*>(&Vl[dh * 32 + nt * 16 + c16][qd * 8]);
      acc[nt] = mfma16(a, bfr, acc[nt]);
    }
    __syncthreads();
  }
#pragma unroll
  for (int nt = 0; nt < 2; nt++) {
    int d = dh * 32 + nt * 16 + c16;
#pragma unroll
    for (int r = 0; r < 4; r++) {
      int q = q0 + mt * 16 + qd * 4 + r;
      size_t off = ((size_t)b * S_ + q) * HS_ + h * 64 + d;
      ctx[off] = f2b(acc[nt][r] + ctx_rel[off]);
    }
  }
}

// ---------------------------------------------------------------------------
// K5: out0 = ctx @ Wo^T + bo   (f32)
__global__ __launch_bounds__(256) void k_oproj(
    const short* __restrict__ ctx, const float* __restrict__ Wo,
    const float* __restrict__ bo, float* __restrict__ out0) {
  int m0 = blockIdx.y * 64, n0 = blockIdx.x * 64;
  int tid = threadIdx.x, wave = tid >> 6, lane = tid & 63;
  int qd = lane >> 4, c16 = lane & 15;
  __shared__ short Wl[64][40];
  floatx4 acc[4] = {};
  const short* arow = ctx + (size_t)(m0 + wave * 16 + c16) * HS_ + qd * 8;
  int sn = tid >> 2, sk = (tid & 3) * 8;
  const float* wrow = Wo + (size_t)(n0 + sn) * HS_ + sk;
  for (int kc = 0; kc < HS_; kc += 32) {
    short8 wsv = cvt8(wrow + kc);
    *reinterpret_cast<short8*>(&Wl[sn][sk]) = wsv;
    __syncthreads();
    short8 a = load_s8(arow + kc);
#pragma unroll
    for (int nt = 0; nt < 4; nt++) {
      short8 b = *reinterpret_cast<const short8*>(&Wl[nt * 16 + c16][qd * 8]);
      acc[nt] = mfma16(a, b, acc[nt]);
    }
    __syncthreads();
  }
#pragma unroll
  for (int nt = 0; nt < 4; nt++) {
    int col = n0 + nt * 16 + c16;
    float bsum = bo[col];
#pragma unroll
    for (int r = 0; r < 4; r++) {
      int row = m0 + wave * 16 + qd * 4 + r;
      out0[(size_t)row * HS_ + col] = acc[nt][r] + bsum;
    }
  }
}

// ---------------------------------------------------------------------------
// K6: out = LayerNorm(out0 + residual) * g + b
__global__ __launch_bounds__(256) void k_ln(
    const float* __restrict__ out0, const float* __restrict__ resid,
    const float* __restrict__ g, const float* __restrict__ bb,
    float* __restrict__ out) {
  int row = blockIdx.x;
  int tid = threadIdx.x, wave = tid >> 6, lane = tid & 63;
  const floatx4* x4 = reinterpret_cast<const floatx4*>(out0 + (size_t)row * HS_);
  const floatx4* r4 = reinterpret_cast<const floatx4*>(resid + (size_t)row * HS_);
  floatx4 x = x4[tid] + r4[tid];
  float s = x[0] + x[1] + x[2] + x[3];
  float ss = x[0]*x[0] + x[1]*x[1] + x[2]*x[2] + x[3]*x[3];
  __shared__ float red[8];
#pragma unroll
  for (int off = 32; off > 0; off >>= 1) {
    s += __shfl_xor(s, off);
    ss += __shfl_xor(ss, off);
  }
  if (lane == 0) { red[wave] = s; red[wave + 4] = ss; }
  __syncthreads();
  s = red[0] + red[1] + red[2] + red[3];
  ss = red[4] + red[5] + red[6] + red[7];
  float mu = s * (1.f / 1024.f);
  float var = ss * (1.f / 1024.f) - mu * mu;
  float rs = rsqrtf(var + 1e-5f);
  int c = tid * 4;
  floatx4 gg = *reinterpret_cast<const floatx4*>(g + c);
  floatx4 bv = *reinterpret_cast<const floatx4*>(bb + c);
  floatx4 y = (x - mu) * rs * gg + bv;
  reinterpret_cast<floatx4*>(out + (size_t)row * HS_)[tid] = y;
}

// ---------------------------------------------------------------------------
extern "C" void kernel_launch(void* const* d_in, const int* in_sizes, int n_in,
                              void* d_out, int out_size, void* d_ws, size_t ws_size,
                              hipStream_t stream) {
  const float* q   = (const float*)d_in[0];
  const float* k   = (const float*)d_in[1];
  const float* v   = (const float*)d_in[2];
  const int*   rp  = (const int*)d_in[3];
  const float* Wq  = (const float*)d_in[4];
  const float* bq  = (const float*)d_in[5];
  const float* Wk  = (const float*)d_in[6];
  const float* bk  = (const float*)d_in[7];
  const float* Wv  = (const float*)d_in[8];
  const float* bv  = (const float*)d_in[9];
  const float* rke = (const float*)d_in[10];
  const float* rve = (const float*)d_in[11];
  const float* Wo  = (const float*)d_in[12];
  const float* bo  = (const float*)d_in[13];
  const float* lng = (const float*)d_in[14];
  const float* lnb = (const float*)d_in[15];

  float* out = (float*)d_out;                         // (B,S,HS) f32
  float* weights = out + (size_t)B_ * S_ * HS_;       // (B,H,S,S) f32

  // workspace layout (bytes) — offsets audited for non-overlap:
  //   qh      [ 0        ,  4194304)
  //   kh      [ 4194304  ,  8388608)
  //   vhT     [ 8388608  , 12582912)
  //   ctx     [12582912  , 16777216)
  //   rveB    [16777216  , 16908416)   V_*D_*2  = 131200
  //   rkeB    [16912384  , 17043584)   V_*D_*2  = 131200
  //   ctx_rel [17043968  , 25432576)   8 MB (256-aligned, after rkeB end)
  //   out0    [25432576  , 33821184)   8 MB
  char* ws = (char*)d_ws;
  short* qh      = (short*)(ws);
  short* kh      = (short*)(ws + 4194304);
  short* vhT     = (short*)(ws + 8388608);
  short* ctx     = (short*)(ws + 12582912);
  short* rveB    = (short*)(ws + 16777216);
  short* rkeB    = (short*)(ws + 16912384);
  float* ctx_rel = (float*)(ws + 17043968);
  float* out0    = (float*)(ws + 25432576);

  k_prep    <<<dim3(513),        256, 0, stream>>>(rve, rke, rveB, rkeB);
  k_proj    <<<dim3(16, 32, 3),  256, 0, stream>>>(q, k, v, Wq, bq, Wk, bk, Wv, bv, qh, kh, vhT);
  k_score   <<<dim3(64, 32),     256, 0, stream>>>(qh, kh, rkeB, rp, weights);
  k_relgemm <<<dim3(1024),       256, 0, stream>>>(weights, rp, rveB, ctx_rel);
  k_ctx2    <<<dim3(32, 32),     256, 0, stream>>>(weights, vhT, ctx_rel, ctx);
  k_oproj   <<<dim3(16, 32),     256, 0, stream>>>(ctx, Wo, bo, out0);
  k_ln      <<<dim3(2048),       256, 0, stream>>>(out0, q, lng, lnb, out);
}

// Round 5
// 414.902 us; speedup vs baseline: 1.4742x; 1.0791x over previous
//
#include <hip/hip_runtime.h>
#include <hip/hip_bf16.h>
#include <stdint.h>

// Problem constants
#define B_   2
#define S_   1024
#define HS_  1024
#define H_   16
#define D_   64
#define V_   1025   // vocab = 2*512+1
#define VP_  1056   // vocab padded to multiple of 32
#define BH_  32     // B_*H_
#define RTS_S 1072  // bf16 Rtile row stride (shorts), k_score
#define RVS_  66    // Rv tile row stride (shorts), k_relgemm

typedef __attribute__((ext_vector_type(8))) short  short8;
typedef __attribute__((ext_vector_type(4))) short  short4v;
typedef __attribute__((ext_vector_type(4))) float  floatx4;
typedef __attribute__((ext_vector_type(4))) int    intx4;
typedef __bf16 bf16x8 __attribute__((ext_vector_type(8)));

// f32 -> bf16 (RNE), bit pattern as short
__device__ inline short f2b(float f) {
  union { float f; uint32_t u; } c; c.f = f;
  uint32_t u = c.u;
  uint32_t r = (u + 0x7fffu + ((u >> 16) & 1u)) >> 16;
  return (short)r;
}
__device__ inline float b2f(short s) {
  union { uint32_t u; float f; } c; c.u = ((uint32_t)(uint16_t)s) << 16;
  return c.f;
}
// load 8 f32 (32B) and convert to bf16x8 (as short8)
__device__ inline short8 cvt8(const float* p) {
  const floatx4* p4 = reinterpret_cast<const floatx4*>(p);
  floatx4 x = p4[0], y = p4[1];
  short8 r;
  r[0]=f2b(x[0]); r[1]=f2b(x[1]); r[2]=f2b(x[2]); r[3]=f2b(x[3]);
  r[4]=f2b(y[0]); r[5]=f2b(y[1]); r[6]=f2b(y[2]); r[7]=f2b(y[3]);
  return r;
}
__device__ inline short8 load_s8(const short* p) {
  return *reinterpret_cast<const short8*>(p);
}
__device__ inline floatx4 mfma16(short8 a, short8 b, floatx4 c) {
  return __builtin_amdgcn_mfma_f32_16x16x32_bf16(
      __builtin_bit_cast(bf16x8, a), __builtin_bit_cast(bf16x8, b), c, 0, 0, 0);
}

// ---------------------------------------------------------------------------
// K0: prep embeddings (both p-major bf16):
//   rveB[p][d] = rve[p][d] bf16
//   rkeB[p][d] = rke[p][d] bf16
__global__ __launch_bounds__(256) void k_prep(const float* __restrict__ rve,
                                              const float* __restrict__ rke,
                                              short* __restrict__ rveB,
                                              short* __restrict__ rkeB) {
  int idx = blockIdx.x * 256 + threadIdx.x;
  if (idx < V_ * D_) {
    rveB[idx] = f2b(rve[idx]);
  } else {
    int j = idx - V_ * D_;
    if (j < V_ * D_) rkeB[j] = f2b(rke[j]);
  }
}

// ---------------------------------------------------------------------------
// K0b: bulk f32->bf16 conversion of GEMM inputs:
//   z=0..2: q,k,v -> xb[z]  (2048x1024 each)
//   z=3..6: Wq,Wk,Wv,Wo -> wb[z-3]  (1024x1024 each, rows = output col)
__global__ __launch_bounds__(256) void k_cvt(
    const float* __restrict__ q, const float* __restrict__ k, const float* __restrict__ v,
    const float* __restrict__ Wq, const float* __restrict__ Wk,
    const float* __restrict__ Wv, const float* __restrict__ Wo,
    short* __restrict__ xb, short* __restrict__ wb) {
  int z = blockIdx.z;
  const float* src = z == 0 ? q : z == 1 ? k : z == 2 ? v
                   : z == 3 ? Wq : z == 4 ? Wk : z == 5 ? Wv : Wo;
  int n = (z < 3) ? (1 << 21) : (1 << 20);
  short* dst = (z < 3) ? xb + (size_t)z * (1 << 21) : wb + (size_t)(z - 3) * (1 << 20);
  int i = (blockIdx.x * 256 + threadIdx.x) * 8;
  if (i < n) *reinterpret_cast<short8*>(&dst[i]) = cvt8(src + i);
}

// ---------------------------------------------------------------------------
// Shared GEMM template: 64x64 tile, BK=32, 4 waves (2x2), acc[2][2].
// LDS K-major [kk][64][8] -> conflict-free ds_read_b128 fragment loads.
// Global loads issued before barrier (overlap with prev MFMA phase).

// K1: projections from pre-converted bf16 inputs.
//   which=0: qh = x@Wq^T+bq ; which=1: kh ; which=2: vhT[b][h][d][s]
__global__ __launch_bounds__(256, 4) void k_proj(
    const short* __restrict__ xb, const short* __restrict__ wb,
    const float* __restrict__ bq, const float* __restrict__ bk, const float* __restrict__ bv,
    short* __restrict__ qh, short* __restrict__ kh, short* __restrict__ vhT) {
  int which = blockIdx.z;
  const short* A  = xb + (size_t)which * (2048u * 1024u);
  const short* Bm = wb + (size_t)which * (1024u * 1024u);
  const float* bias = which == 0 ? bq : which == 1 ? bk : bv;
  int m0 = blockIdx.x * 64, n0 = blockIdx.y * 64;
  int tid = threadIdx.x, wid = tid >> 6, lane = tid & 63;
  int wr = wid >> 1, wc = wid & 1, qd = lane >> 4, c16 = lane & 15;
  __shared__ short As[4 * 64 * 8];
  __shared__ short Bs[4 * 64 * 8];
  int kk = tid & 3, rowi = tid >> 2;
  const short* ga = A  + (size_t)(m0 + rowi) * HS_ + kk * 8;
  const short* gb = Bm + (size_t)(n0 + rowi) * HS_ + kk * 8;
  floatx4 acc[2][2] = {};
  for (int k0 = 0; k0 < HS_; k0 += 32) {
    short8 av = load_s8(ga + k0);
    short8 bv8 = load_s8(gb + k0);
    __syncthreads();
    *reinterpret_cast<short8*>(&As[kk * 512 + rowi * 8]) = av;
    *reinterpret_cast<short8*>(&Bs[kk * 512 + rowi * 8]) = bv8;
    __syncthreads();
    short8 a0 = load_s8(&As[qd * 512 + (wr * 32 + c16) * 8]);
    short8 a1 = load_s8(&As[qd * 512 + (wr * 32 + 16 + c16) * 8]);
    short8 b0 = load_s8(&Bs[qd * 512 + (wc * 32 + c16) * 8]);
    short8 b1 = load_s8(&Bs[qd * 512 + (wc * 32 + 16 + c16) * 8]);
    acc[0][0] = mfma16(a0, b0, acc[0][0]);
    acc[0][1] = mfma16(a0, b1, acc[0][1]);
    acc[1][0] = mfma16(a1, b0, acc[1][0]);
    acc[1][1] = mfma16(a1, b1, acc[1][1]);
  }
#pragma unroll
  for (int mi = 0; mi < 2; mi++)
#pragma unroll
    for (int ni = 0; ni < 2; ni++) {
      int col = n0 + wc * 32 + ni * 16 + c16;
      float bs = bias[col];
      int gr0 = m0 + wr * 32 + mi * 16 + qd * 4;
      if (which < 2) {
        short* dst = which == 0 ? qh : kh;
#pragma unroll
        for (int r = 0; r < 4; r++)
          dst[(size_t)(gr0 + r) * HS_ + col] = f2b(acc[mi][ni][r] + bs);
      } else {
        int h = col >> 6, d = col & 63;
        int bb = gr0 >> 10, s = gr0 & 1023;
        short4v pk;
#pragma unroll
        for (int r = 0; r < 4; r++) pk[r] = f2b(acc[mi][ni][r] + bs);
        *reinterpret_cast<short4v*>(&vhT[(((size_t)(bb * H_ + h)) * D_ + d) * S_ + s]) = pk;
      }
    }
}

// ---------------------------------------------------------------------------
// K3a: scores for one (b,h, 16-q tile)  [unchanged, proven]
__global__ __launch_bounds__(256, 4) void k_score(
    const short* __restrict__ qh, const short* __restrict__ kh,
    const short* __restrict__ rkeB, const int* __restrict__ rp,
    float* __restrict__ weights) {
  int bh = blockIdx.y;
  int b = bh >> 4, h = bh & 15;
  int q0 = blockIdx.x * 16;
  int tid = threadIdx.x, wave = tid >> 6, lane = tid & 63;
  int qd = lane >> 4, c16 = lane & 15;
  __shared__ short Rt[16 * RTS_S];   // bf16 Rtile
  __shared__ float redA[4 * 16];
  __shared__ float redB[4 * 16];

  const short* aptr = qh + ((size_t)b * S_ + q0 + c16) * HS_ + h * 64 + qd * 8;
  short8 a0 = load_s8(aptr), a1 = load_s8(aptr + 32);

  for (int nt = wave; nt < VP_ / 16; nt += 4) {
    int p = nt * 16 + c16;
    short8 b0 = {}, b1 = {};
    if (p < V_) {
      b0 = load_s8(rkeB + (size_t)p * D_ + qd * 8);
      b1 = load_s8(rkeB + (size_t)p * D_ + 32 + qd * 8);
    }
    floatx4 acc = {};
    acc = mfma16(a0, b0, acc);
    acc = mfma16(a1, b1, acc);
#pragma unroll
    for (int r = 0; r < 4; r++) Rt[(qd * 4 + r) * RTS_S + p] = f2b(acc[r]);
  }
  __syncthreads();

  floatx4 acc[16];
  const int* rpq = rp + (size_t)q0 * S_;
#pragma unroll
  for (int it = 0; it < 16; it++) {
    int col = wave * 256 + it * 16 + c16;
    const short* bptr = kh + ((size_t)b * S_ + col) * HS_ + h * 64 + qd * 8;
    floatx4 a = {};
    a = mfma16(a0, load_s8(bptr), a);
    a = mfma16(a1, load_s8(bptr + 32), a);
#pragma unroll
    for (int r = 0; r < 4; r++) {
      int row = qd * 4 + r;
      int p = rpq[(size_t)row * S_ + col];
      a[r] += b2f(Rt[row * RTS_S + p]);
    }
    acc[it] = a;
  }

  float mx[4], inv[4];
#pragma unroll
  for (int r = 0; r < 4; r++) {
    float m = -1e30f;
#pragma unroll
    for (int it = 0; it < 16; it++) m = fmaxf(m, acc[it][r]);
#pragma unroll
    for (int off = 1; off < 16; off <<= 1) m = fmaxf(m, __shfl_xor(m, off));
    mx[r] = m;
    if (c16 == 0) redA[wave * 16 + qd * 4 + r] = m;
  }
  __syncthreads();
#pragma unroll
  for (int r = 0; r < 4; r++) {
    int row = qd * 4 + r;
    float m = fmaxf(fmaxf(redA[row], redA[16 + row]),
                    fmaxf(redA[32 + row], redA[48 + row]));
    mx[r] = m;
  }
  float sm[4] = {0.f, 0.f, 0.f, 0.f};
#pragma unroll
  for (int it = 0; it < 16; it++) {
#pragma unroll
    for (int r = 0; r < 4; r++) {
      float e = __expf(acc[it][r] - mx[r]);
      acc[it][r] = e;
      sm[r] += e;
    }
  }
#pragma unroll
  for (int r = 0; r < 4; r++) {
#pragma unroll
    for (int off = 1; off < 16; off <<= 1) sm[r] += __shfl_xor(sm[r], off);
    if (c16 == 0) redB[wave * 16 + qd * 4 + r] = sm[r];
  }
  __syncthreads();
#pragma unroll
  for (int r = 0; r < 4; r++) {
    int row = qd * 4 + r;
    inv[r] = 1.f / (redB[row] + redB[16 + row] + redB[32 + row] + redB[48 + row]);
  }

  float* wout = weights + (size_t)bh * S_ * S_ + (size_t)q0 * S_;
#pragma unroll
  for (int it = 0; it < 16; it++) {
    int col = wave * 256 + it * 16 + c16;
#pragma unroll
    for (int r = 0; r < 4; r++) {
      wout[(size_t)(qd * 4 + r) * S_ + col] = acc[it][r] * inv[r];
    }
  }
}

// ---------------------------------------------------------------------------
// K3b: relative-value context as a per-q GEMM  [unchanged, proven]
__global__ __launch_bounds__(256, 4) void k_relgemm(
    const float* __restrict__ weights, const int* __restrict__ rp,
    const short* __restrict__ rveB, float* __restrict__ ctx_rel) {
  int q = blockIdx.x;
  int tid = threadIdx.x, wave = tid >> 6, lane = tid & 63;
  int qd = lane >> 4, c16 = lane & 15;
  __shared__ int   rpl[S_];
  __shared__ short Wl[32][40];
  __shared__ short Rv[32][RVS_];

  {
    const intx4* r4 = reinterpret_cast<const intx4*>(rp + (size_t)q * S_);
    reinterpret_cast<intx4*>(rpl)[tid] = r4[tid];
  }
  __syncthreads();

  int sn = tid >> 3;
  int sk = (tid & 3) * 8;   // unused path kept simple below
  int part = tid & 7;
  const float* wbase = weights + ((size_t)sn * S_ + q) * S_;
  floatx4 acc0 = {}, acc1 = {};
  int d0 = wave * 16;

  for (int kc = 0; kc < S_; kc += 32) {
    {
      int skA = (tid & 7) * 4;
      floatx4 wv = *reinterpret_cast<const floatx4*>(wbase + kc + skA);
      short4v pk;
      pk[0] = f2b(wv[0]); pk[1] = f2b(wv[1]);
      pk[2] = f2b(wv[2]); pk[3] = f2b(wv[3]);
      *reinterpret_cast<short4v*>(&Wl[sn][skA]) = pk;
    }
    {
      int p = rpl[kc + sn];
      *reinterpret_cast<short8*>(&Rv[sn][part * 8]) =
          load_s8(rveB + (size_t)p * D_ + part * 8);
    }
    __syncthreads();
    short8 a0 = *reinterpret_cast<const short8*>(&Wl[c16][qd * 8]);
    short8 a1 = *reinterpret_cast<const short8*>(&Wl[16 + c16][qd * 8]);
    short8 bfr;
#pragma unroll
    for (int j = 0; j < 8; j++) bfr[j] = Rv[qd * 8 + j][d0 + c16];
    acc0 = mfma16(a0, bfr, acc0);
    acc1 = mfma16(a1, bfr, acc1);
    __syncthreads();
  }

  int dd = d0 + c16;
#pragma unroll
  for (int r = 0; r < 4; r++) {
    int bh0 = qd * 4 + r;
    ctx_rel[((size_t)0 * S_ + q) * HS_ + bh0 * 64 + dd] = acc0[r];
    ctx_rel[((size_t)1 * S_ + q) * HS_ + bh0 * 64 + dd] = acc1[r];
  }
}

// ---------------------------------------------------------------------------
// K4: content GEMM + add: ctx = bf16(weights @ vhT + ctx_rel)
//   Template: 64q x 64d tile per (bh, q-block); A = weights f32 (cvt in stage)
__global__ __launch_bounds__(256, 4) void k_ctx2(
    const float* __restrict__ weights, const short* __restrict__ vhT,
    const float* __restrict__ ctx_rel, short* __restrict__ ctx) {
  int bh = blockIdx.y;
  int b = bh >> 4, h = bh & 15;
  int m0 = blockIdx.x * 64;
  int tid = threadIdx.x, wid = tid >> 6, lane = tid & 63;
  int wr = wid >> 1, wc = wid & 1, qd = lane >> 4, c16 = lane & 15;
  __shared__ short As[4 * 64 * 8];
  __shared__ short Bs[4 * 64 * 8];
  int kk = tid & 3, rowi = tid >> 2;
  const float* gaf = weights + (size_t)bh * S_ * S_ + (size_t)(m0 + rowi) * S_ + kk * 8;
  const short* gb  = vhT + ((size_t)bh * D_ + rowi) * S_ + kk * 8;
  floatx4 acc[2][2] = {};
  for (int k0 = 0; k0 < S_; k0 += 32) {
    short8 av = cvt8(gaf + k0);
    short8 bv8 = load_s8(gb + k0);
    __syncthreads();
    *reinterpret_cast<short8*>(&As[kk * 512 + rowi * 8]) = av;
    *reinterpret_cast<short8*>(&Bs[kk * 512 + rowi * 8]) = bv8;
    __syncthreads();
    short8 a0 = load_s8(&As[qd * 512 + (wr * 32 + c16) * 8]);
    short8 a1 = load_s8(&As[qd * 512 + (wr * 32 + 16 + c16) * 8]);
    short8 b0 = load_s8(&Bs[qd * 512 + (wc * 32 + c16) * 8]);
    short8 b1 = load_s8(&Bs[qd * 512 + (wc * 32 + 16 + c16) * 8]);
    acc[0][0] = mfma16(a0, b0, acc[0][0]);
    acc[0][1] = mfma16(a0, b1, acc[0][1]);
    acc[1][0] = mfma16(a1, b0, acc[1][0]);
    acc[1][1] = mfma16(a1, b1, acc[1][1]);
  }
#pragma unroll
  for (int mi = 0; mi < 2; mi++)
#pragma unroll
    for (int ni = 0; ni < 2; ni++) {
      int d = wc * 32 + ni * 16 + c16;
      int gq0 = m0 + wr * 32 + mi * 16 + qd * 4;
#pragma unroll
      for (int r = 0; r < 4; r++) {
        size_t off = ((size_t)b * S_ + gq0 + r) * HS_ + h * 64 + d;
        ctx[off] = f2b(acc[mi][ni][r] + ctx_rel[off]);
      }
    }
}

// ---------------------------------------------------------------------------
// K5: out0 = ctx @ Wo^T + bo   (f32)  — template, bf16 A (ctx) and B (wob)
__global__ __launch_bounds__(256, 4) void k_oproj(
    const short* __restrict__ ctx, const short* __restrict__ wob,
    const float* __restrict__ bo, float* __restrict__ out0) {
  int m0 = blockIdx.x * 64, n0 = blockIdx.y * 64;
  int tid = threadIdx.x, wid = tid >> 6, lane = tid & 63;
  int wr = wid >> 1, wc = wid & 1, qd = lane >> 4, c16 = lane & 15;
  __shared__ short As[4 * 64 * 8];
  __shared__ short Bs[4 * 64 * 8];
  int kk = tid & 3, rowi = tid >> 2;
  const short* ga = ctx + (size_t)(m0 + rowi) * HS_ + kk * 8;
  const short* gb = wob + (size_t)(n0 + rowi) * HS_ + kk * 8;
  floatx4 acc[2][2] = {};
  for (int k0 = 0; k0 < HS_; k0 += 32) {
    short8 av = load_s8(ga + k0);
    short8 bv8 = load_s8(gb + k0);
    __syncthreads();
    *reinterpret_cast<short8*>(&As[kk * 512 + rowi * 8]) = av;
    *reinterpret_cast<short8*>(&Bs[kk * 512 + rowi * 8]) = bv8;
    __syncthreads();
    short8 a0 = load_s8(&As[qd * 512 + (wr * 32 + c16) * 8]);
    short8 a1 = load_s8(&As[qd * 512 + (wr * 32 + 16 + c16) * 8]);
    short8 b0 = load_s8(&Bs[qd * 512 + (wc * 32 + c16) * 8]);
    short8 b1 = load_s8(&Bs[qd * 512 + (wc * 32 + 16 + c16) * 8]);
    acc[0][0] = mfma16(a0, b0, acc[0][0]);
    acc[0][1] = mfma16(a0, b1, acc[0][1]);
    acc[1][0] = mfma16(a1, b0, acc[1][0]);
    acc[1][1] = mfma16(a1, b1, acc[1][1]);
  }
#pragma unroll
  for (int mi = 0; mi < 2; mi++)
#pragma unroll
    for (int ni = 0; ni < 2; ni++) {
      int col = n0 + wc * 32 + ni * 16 + c16;
      float bs = bo[col];
      int gr0 = m0 + wr * 32 + mi * 16 + qd * 4;
#pragma unroll
      for (int r = 0; r < 4; r++)
        out0[(size_t)(gr0 + r) * HS_ + col] = acc[mi][ni][r] + bs;
    }
}

// ---------------------------------------------------------------------------
// K6: out = LayerNorm(out0 + residual) * g + b   [unchanged]
__global__ __launch_bounds__(256) void k_ln(
    const float* __restrict__ out0, const float* __restrict__ resid,
    const float* __restrict__ g, const float* __restrict__ bb,
    float* __restrict__ out) {
  int row = blockIdx.x;
  int tid = threadIdx.x, wave = tid >> 6, lane = tid & 63;
  const floatx4* x4 = reinterpret_cast<const floatx4*>(out0 + (size_t)row * HS_);
  const floatx4* r4 = reinterpret_cast<const floatx4*>(resid + (size_t)row * HS_);
  floatx4 x = x4[tid] + r4[tid];
  float s = x[0] + x[1] + x[2] + x[3];
  float ss = x[0]*x[0] + x[1]*x[1] + x[2]*x[2] + x[3]*x[3];
  __shared__ float red[8];
#pragma unroll
  for (int off = 32; off > 0; off >>= 1) {
    s += __shfl_xor(s, off);
    ss += __shfl_xor(ss, off);
  }
  if (lane == 0) { red[wave] = s; red[wave + 4] = ss; }
  __syncthreads();
  s = red[0] + red[1] + red[2] + red[3];
  ss = red[4] + red[5] + red[6] + red[7];
  float mu = s * (1.f / 1024.f);
  float var = ss * (1.f / 1024.f) - mu * mu;
  float rs = rsqrtf(var + 1e-5f);
  int c = tid * 4;
  floatx4 gg = *reinterpret_cast<const floatx4*>(g + c);
  floatx4 bv = *reinterpret_cast<const floatx4*>(bb + c);
  floatx4 y = (x - mu) * rs * gg + bv;
  reinterpret_cast<floatx4*>(out + (size_t)row * HS_)[tid] = y;
}

// ---------------------------------------------------------------------------
extern "C" void kernel_launch(void* const* d_in, const int* in_sizes, int n_in,
                              void* d_out, int out_size, void* d_ws, size_t ws_size,
                              hipStream_t stream) {
  const float* q   = (const float*)d_in[0];
  const float* k   = (const float*)d_in[1];
  const float* v   = (const float*)d_in[2];
  const int*   rp  = (const int*)d_in[3];
  const float* Wq  = (const float*)d_in[4];
  const float* bq  = (const float*)d_in[5];
  const float* Wk  = (const float*)d_in[6];
  const float* bk  = (const float*)d_in[7];
  const float* Wv  = (const float*)d_in[8];
  const float* bv  = (const float*)d_in[9];
  const float* rke = (const float*)d_in[10];
  const float* rve = (const float*)d_in[11];
  const float* Wo  = (const float*)d_in[12];
  const float* bo  = (const float*)d_in[13];
  const float* lng = (const float*)d_in[14];
  const float* lnb = (const float*)d_in[15];

  float* out = (float*)d_out;                         // (B,S,HS) f32
  float* weights = out + (size_t)B_ * S_ * HS_;       // (B,H,S,S) f32

  // workspace layout (bytes) — offsets audited for non-overlap:
  //   qh      [ 0        ,  4194304)
  //   kh      [ 4194304  ,  8388608)
  //   vhT     [ 8388608  , 12582912)
  //   ctx     [12582912  , 16777216)
  //   rveB    [16777216  , 16908416)   V_*D_*2  = 131200
  //   rkeB    [16912384  , 17043584)   V_*D_*2  = 131200
  //   ctx_rel [17043968  , 25432576)   8 MB
  //   out0    [25432576  , 33821184)   8 MB
  //   xb      [33821184  , 46404096)   3*2M*2 = 12 MB
  //   wb      [46404096  , 54792704)   4*1M*2 = 8 MB
  char* ws = (char*)d_ws;
  short* qh      = (short*)(ws);
  short* kh      = (short*)(ws + 4194304);
  short* vhT     = (short*)(ws + 8388608);
  short* ctx     = (short*)(ws + 12582912);
  short* rveB    = (short*)(ws + 16777216);
  short* rkeB    = (short*)(ws + 16912384);
  float* ctx_rel = (float*)(ws + 17043968);
  float* out0    = (float*)(ws + 25432576);
  short* xb      = (short*)(ws + 33821184);
  short* wb      = (short*)(ws + 46404096);
  short* wob     = wb + (size_t)3 * (1 << 20);

  k_prep    <<<dim3(513),        256, 0, stream>>>(rve, rke, rveB, rkeB);
  k_cvt     <<<dim3(1024, 1, 7), 256, 0, stream>>>(q, k, v, Wq, Wk, Wv, Wo, xb, wb);
  k_proj    <<<dim3(32, 16, 3),  256, 0, stream>>>(xb, wb, bq, bk, bv, qh, kh, vhT);
  k_score   <<<dim3(64, 32),     256, 0, stream>>>(qh, kh, rkeB, rp, weights);
  k_relgemm <<<dim3(1024),       256, 0, stream>>>(weights, rp, rveB, ctx_rel);
  k_ctx2    <<<dim3(16, 32),     256, 0, stream>>>(weights, vhT, ctx_rel, ctx);
  k_oproj   <<<dim3(32, 16),     256, 0, stream>>>(ctx, wob, bo, out0);
  k_ln      <<<dim3(2048),       256, 0, stream>>>(out0, q, lng, lnb, out);
}

// Round 6
// 386.003 us; speedup vs baseline: 1.5846x; 1.0749x over previous
//
#include <hip/hip_runtime.h>
#include <hip/hip_bf16.h>
#include <stdint.h>

// Problem constants
#define B_   2
#define S_   1024
#define HS_  1024
#define H_   16
#define D_   64
#define V_   1025   // vocab = 2*512+1
#define VP_  1056   // vocab padded to multiple of 32
#define BH_  32     // B_*H_
#define PTS_ 1096   // k_score SH row stride (shorts): 548 dwords, %32==4 -> 2-way banks
#define RVS_ 66     // Rv tile row stride (shorts), k_relgemm

typedef __attribute__((ext_vector_type(8))) short  short8;
typedef __attribute__((ext_vector_type(4))) short  short4v;
typedef __attribute__((ext_vector_type(4))) float  floatx4;
typedef __attribute__((ext_vector_type(4))) int    intx4;
typedef __bf16 bf16x8 __attribute__((ext_vector_type(8)));

// f32 -> bf16 (RNE), bit pattern as short
__device__ inline short f2b(float f) {
  union { float f; uint32_t u; } c; c.f = f;
  uint32_t u = c.u;
  uint32_t r = (u + 0x7fffu + ((u >> 16) & 1u)) >> 16;
  return (short)r;
}
__device__ inline float b2f(short s) {
  union { uint32_t u; float f; } c; c.u = ((uint32_t)(uint16_t)s) << 16;
  return c.f;
}
// load 8 f32 (32B) and convert to bf16x8 (as short8)
__device__ inline short8 cvt8(const float* p) {
  const floatx4* p4 = reinterpret_cast<const floatx4*>(p);
  floatx4 x = p4[0], y = p4[1];
  short8 r;
  r[0]=f2b(x[0]); r[1]=f2b(x[1]); r[2]=f2b(x[2]); r[3]=f2b(x[3]);
  r[4]=f2b(y[0]); r[5]=f2b(y[1]); r[6]=f2b(y[2]); r[7]=f2b(y[3]);
  return r;
}
__device__ inline short8 load_s8(const short* p) {
  return *reinterpret_cast<const short8*>(p);
}
__device__ inline floatx4 mfma16(short8 a, short8 b, floatx4 c) {
  return __builtin_amdgcn_mfma_f32_16x16x32_bf16(
      __builtin_bit_cast(bf16x8, a), __builtin_bit_cast(bf16x8, b), c, 0, 0, 0);
}

// ---------------------------------------------------------------------------
// K0: prep embeddings (both p-major bf16)
__global__ __launch_bounds__(256) void k_prep(const float* __restrict__ rve,
                                              const float* __restrict__ rke,
                                              short* __restrict__ rveB,
                                              short* __restrict__ rkeB) {
  int idx = blockIdx.x * 256 + threadIdx.x;
  if (idx < V_ * D_) {
    rveB[idx] = f2b(rve[idx]);
  } else {
    int j = idx - V_ * D_;
    if (j < V_ * D_) rkeB[j] = f2b(rke[j]);
  }
}

// ---------------------------------------------------------------------------
// K0b: bulk f32->bf16 conversion of GEMM inputs
__global__ __launch_bounds__(256) void k_cvt(
    const float* __restrict__ q, const float* __restrict__ k, const float* __restrict__ v,
    const float* __restrict__ Wq, const float* __restrict__ Wk,
    const float* __restrict__ Wv, const float* __restrict__ Wo,
    short* __restrict__ xb, short* __restrict__ wb) {
  int z = blockIdx.z;
  const float* src = z == 0 ? q : z == 1 ? k : z == 2 ? v
                   : z == 3 ? Wq : z == 4 ? Wk : z == 5 ? Wv : Wo;
  int n = (z < 3) ? (1 << 21) : (1 << 20);
  short* dst = (z < 3) ? xb + (size_t)z * (1 << 21) : wb + (size_t)(z - 3) * (1 << 20);
  int i = (blockIdx.x * 256 + threadIdx.x) * 8;
  if (i < n) *reinterpret_cast<short8*>(&dst[i]) = cvt8(src + i);
}

// ---------------------------------------------------------------------------
// K1: projections from pre-converted bf16 inputs. [unchanged from round 5]
__global__ __launch_bounds__(256, 4) void k_proj(
    const short* __restrict__ xb, const short* __restrict__ wb,
    const float* __restrict__ bq, const float* __restrict__ bk, const float* __restrict__ bv,
    short* __restrict__ qh, short* __restrict__ kh, short* __restrict__ vhT) {
  int which = blockIdx.z;
  const short* A  = xb + (size_t)which * (2048u * 1024u);
  const short* Bm = wb + (size_t)which * (1024u * 1024u);
  const float* bias = which == 0 ? bq : which == 1 ? bk : bv;
  int m0 = blockIdx.x * 64, n0 = blockIdx.y * 64;
  int tid = threadIdx.x, wid = tid >> 6, lane = tid & 63;
  int wr = wid >> 1, wc = wid & 1, qd = lane >> 4, c16 = lane & 15;
  __shared__ short As[4 * 64 * 8];
  __shared__ short Bs[4 * 64 * 8];
  int kk = tid & 3, rowi = tid >> 2;
  const short* ga = A  + (size_t)(m0 + rowi) * HS_ + kk * 8;
  const short* gb = Bm + (size_t)(n0 + rowi) * HS_ + kk * 8;
  floatx4 acc[2][2] = {};
  for (int k0 = 0; k0 < HS_; k0 += 32) {
    short8 av = load_s8(ga + k0);
    short8 bv8 = load_s8(gb + k0);
    __syncthreads();
    *reinterpret_cast<short8*>(&As[kk * 512 + rowi * 8]) = av;
    *reinterpret_cast<short8*>(&Bs[kk * 512 + rowi * 8]) = bv8;
    __syncthreads();
    short8 a0 = load_s8(&As[qd * 512 + (wr * 32 + c16) * 8]);
    short8 a1 = load_s8(&As[qd * 512 + (wr * 32 + 16 + c16) * 8]);
    short8 b0 = load_s8(&Bs[qd * 512 + (wc * 32 + c16) * 8]);
    short8 b1 = load_s8(&Bs[qd * 512 + (wc * 32 + 16 + c16) * 8]);
    acc[0][0] = mfma16(a0, b0, acc[0][0]);
    acc[0][1] = mfma16(a0, b1, acc[0][1]);
    acc[1][0] = mfma16(a1, b0, acc[1][0]);
    acc[1][1] = mfma16(a1, b1, acc[1][1]);
  }
#pragma unroll
  for (int mi = 0; mi < 2; mi++)
#pragma unroll
    for (int ni = 0; ni < 2; ni++) {
      int col = n0 + wc * 32 + ni * 16 + c16;
      float bs = bias[col];
      int gr0 = m0 + wr * 32 + mi * 16 + qd * 4;
      if (which < 2) {
        short* dst = which == 0 ? qh : kh;
#pragma unroll
        for (int r = 0; r < 4; r++)
          dst[(size_t)(gr0 + r) * HS_ + col] = f2b(acc[mi][ni][r] + bs);
      } else {
        int h = col >> 6, d = col & 63;
        int bb = gr0 >> 10, s = gr0 & 1023;
        short4v pk;
#pragma unroll
        for (int r = 0; r < 4; r++) pk[r] = f2b(acc[mi][ni][r] + bs);
        *reinterpret_cast<short4v*>(&vhT[(((size_t)(bb * H_ + h)) * D_ + d) * S_ + s]) = pk;
      }
    }
}

// ---------------------------------------------------------------------------
// K3a: scores + fused PV for one (b,h, 16-q tile):
//  P0: Rt[16][PTS_] = qh_tile @ rkeB^T  (LDS SH, bf16)
//  P1: logits (registers) = qh.kh^T + Rt[rp gather]
//  P2: softmax in registers
//  P3: write weights (global) + P bf16 into SH (Rt is dead, 2 barriers past)
//  P4: ctxf = P @ vhT  (per wave 16x16x1024, vhT rows L2-resident)
__global__ __launch_bounds__(256, 4) void k_score(
    const short* __restrict__ qh, const short* __restrict__ kh,
    const short* __restrict__ rkeB, const int* __restrict__ rp,
    const short* __restrict__ vhT, float* __restrict__ weights,
    float* __restrict__ ctxf) {
  int bh = blockIdx.y;
  int b = bh >> 4, h = bh & 15;
  int q0 = blockIdx.x * 16;
  int tid = threadIdx.x, wave = tid >> 6, lane = tid & 63;
  int qd = lane >> 4, c16 = lane & 15;
  __shared__ short SH[16 * PTS_];    // Rt (P0-P1), then P (P3-P4)
  __shared__ float redA[4 * 16];
  __shared__ float redB[4 * 16];

  const short* aptr = qh + ((size_t)b * S_ + q0 + c16) * HS_ + h * 64 + qd * 8;
  short8 a0 = load_s8(aptr), a1 = load_s8(aptr + 32);

  // ---- P0: Rt
  for (int nt = wave; nt < VP_ / 16; nt += 4) {
    int p = nt * 16 + c16;
    short8 b0 = {}, b1 = {};
    if (p < V_) {
      b0 = load_s8(rkeB + (size_t)p * D_ + qd * 8);
      b1 = load_s8(rkeB + (size_t)p * D_ + 32 + qd * 8);
    }
    floatx4 acc = {};
    acc = mfma16(a0, b0, acc);
    acc = mfma16(a1, b1, acc);
#pragma unroll
    for (int r = 0; r < 4; r++) SH[(qd * 4 + r) * PTS_ + p] = f2b(acc[r]);
  }
  __syncthreads();

  // ---- P1: logits
  floatx4 acc[16];
  const int* rpq = rp + (size_t)q0 * S_;
#pragma unroll
  for (int it = 0; it < 16; it++) {
    int col = wave * 256 + it * 16 + c16;
    const short* bptr = kh + ((size_t)b * S_ + col) * HS_ + h * 64 + qd * 8;
    floatx4 a = {};
    a = mfma16(a0, load_s8(bptr), a);
    a = mfma16(a1, load_s8(bptr + 32), a);
#pragma unroll
    for (int r = 0; r < 4; r++) {
      int row = qd * 4 + r;
      int p = rpq[(size_t)row * S_ + col];
      a[r] += b2f(SH[row * PTS_ + p]);
    }
    acc[it] = a;
  }

  // ---- P2: softmax
  float mx[4], inv[4];
#pragma unroll
  for (int r = 0; r < 4; r++) {
    float m = -1e30f;
#pragma unroll
    for (int it = 0; it < 16; it++) m = fmaxf(m, acc[it][r]);
#pragma unroll
    for (int off = 1; off < 16; off <<= 1) m = fmaxf(m, __shfl_xor(m, off));
    mx[r] = m;
    if (c16 == 0) redA[wave * 16 + qd * 4 + r] = m;
  }
  __syncthreads();
#pragma unroll
  for (int r = 0; r < 4; r++) {
    int row = qd * 4 + r;
    float m = fmaxf(fmaxf(redA[row], redA[16 + row]),
                    fmaxf(redA[32 + row], redA[48 + row]));
    mx[r] = m;
  }
  float sm[4] = {0.f, 0.f, 0.f, 0.f};
#pragma unroll
  for (int it = 0; it < 16; it++) {
#pragma unroll
    for (int r = 0; r < 4; r++) {
      float e = __expf(acc[it][r] - mx[r]);
      acc[it][r] = e;
      sm[r] += e;
    }
  }
#pragma unroll
  for (int r = 0; r < 4; r++) {
#pragma unroll
    for (int off = 1; off < 16; off <<= 1) sm[r] += __shfl_xor(sm[r], off);
    if (c16 == 0) redB[wave * 16 + qd * 4 + r] = sm[r];
  }
  __syncthreads();
#pragma unroll
  for (int r = 0; r < 4; r++) {
    int row = qd * 4 + r;
    inv[r] = 1.f / (redB[row] + redB[16 + row] + redB[32 + row] + redB[48 + row]);
  }

  // ---- P3: write weights (global) + P (LDS, overwrites Rt region)
  float* wout = weights + (size_t)bh * S_ * S_ + (size_t)q0 * S_;
#pragma unroll
  for (int it = 0; it < 16; it++) {
    int col = wave * 256 + it * 16 + c16;
#pragma unroll
    for (int r = 0; r < 4; r++) {
      int row = qd * 4 + r;
      float w = acc[it][r] * inv[r];
      wout[(size_t)row * S_ + col] = w;
      SH[row * PTS_ + col] = f2b(w);
    }
  }
  __syncthreads();

  // ---- P4: ctxf = P @ vhT (per wave: 16 q x 16 d, K=1024)
  {
    int d0 = wave * 16;
    const short* vb = vhT + ((size_t)bh * D_ + d0 + c16) * S_ + qd * 8;
    floatx4 apv = {};
    for (int kc = 0; kc < S_; kc += 32) {
      short8 pa = load_s8(&SH[c16 * PTS_ + kc + qd * 8]);
      apv = mfma16(pa, load_s8(vb + kc), apv);
    }
    float* cf = ctxf + ((size_t)b * S_ + q0 + qd * 4) * HS_ + h * 64 + d0 + c16;
#pragma unroll
    for (int r = 0; r < 4; r++) cf[(size_t)r * HS_] = apv[r];
  }
}

// ---------------------------------------------------------------------------
// K3b: relative-value context as a per-q GEMM; accumulates += into ctxf
//   (runs after k_score which initialized ctxf; each location owned by 1 lane)
__global__ __launch_bounds__(256, 4) void k_relgemm(
    const float* __restrict__ weights, const int* __restrict__ rp,
    const short* __restrict__ rveB, float* __restrict__ ctxf) {
  int q = blockIdx.x;
  int tid = threadIdx.x, wave = tid >> 6, lane = tid & 63;
  int qd = lane >> 4, c16 = lane & 15;
  __shared__ int   rpl[S_];
  __shared__ short Wl[32][40];
  __shared__ short Rv[32][RVS_];

  {
    const intx4* r4 = reinterpret_cast<const intx4*>(rp + (size_t)q * S_);
    reinterpret_cast<intx4*>(rpl)[tid] = r4[tid];
  }
  __syncthreads();

  int sn = tid >> 3;
  int part = tid & 7;
  const float* wbase = weights + ((size_t)sn * S_ + q) * S_;
  floatx4 acc0 = {}, acc1 = {};
  int d0 = wave * 16;

  for (int kc = 0; kc < S_; kc += 32) {
    {
      int skA = (tid & 7) * 4;
      floatx4 wv = *reinterpret_cast<const floatx4*>(wbase + kc + skA);
      short4v pk;
      pk[0] = f2b(wv[0]); pk[1] = f2b(wv[1]);
      pk[2] = f2b(wv[2]); pk[3] = f2b(wv[3]);
      *reinterpret_cast<short4v*>(&Wl[sn][skA]) = pk;
    }
    {
      int p = rpl[kc + sn];
      *reinterpret_cast<short8*>(&Rv[sn][part * 8]) =
          load_s8(rveB + (size_t)p * D_ + part * 8);
    }
    __syncthreads();
    short8 a0 = *reinterpret_cast<const short8*>(&Wl[c16][qd * 8]);
    short8 a1 = *reinterpret_cast<const short8*>(&Wl[16 + c16][qd * 8]);
    short8 bfr;
#pragma unroll
    for (int j = 0; j < 8; j++) bfr[j] = Rv[qd * 8 + j][d0 + c16];
    acc0 = mfma16(a0, bfr, acc0);
    acc1 = mfma16(a1, bfr, acc1);
    __syncthreads();
  }

  int dd = d0 + c16;
#pragma unroll
  for (int r = 0; r < 4; r++) {
    int bh0 = qd * 4 + r;
    size_t o0 = ((size_t)0 * S_ + q) * HS_ + bh0 * 64 + dd;
    size_t o1 = ((size_t)1 * S_ + q) * HS_ + bh0 * 64 + dd;
    ctxf[o0] += acc0[r];
    ctxf[o1] += acc1[r];
  }
}

// ---------------------------------------------------------------------------
// K5: out0 = ctxf @ Wo^T + bo   (f32 A with cvt-in-stage, bf16 B)
__global__ __launch_bounds__(256, 4) void k_oproj(
    const float* __restrict__ ctxf, const short* __restrict__ wob,
    const float* __restrict__ bo, float* __restrict__ out0) {
  int m0 = blockIdx.x * 64, n0 = blockIdx.y * 64;
  int tid = threadIdx.x, wid = tid >> 6, lane = tid & 63;
  int wr = wid >> 1, wc = wid & 1, qd = lane >> 4, c16 = lane & 15;
  __shared__ short As[4 * 64 * 8];
  __shared__ short Bs[4 * 64 * 8];
  int kk = tid & 3, rowi = tid >> 2;
  const float* ga = ctxf + (size_t)(m0 + rowi) * HS_ + kk * 8;
  const short* gb = wob + (size_t)(n0 + rowi) * HS_ + kk * 8;
  floatx4 acc[2][2] = {};
  for (int k0 = 0; k0 < HS_; k0 += 32) {
    short8 av = cvt8(ga + k0);
    short8 bv8 = load_s8(gb + k0);
    __syncthreads();
    *reinterpret_cast<short8*>(&As[kk * 512 + rowi * 8]) = av;
    *reinterpret_cast<short8*>(&Bs[kk * 512 + rowi * 8]) = bv8;
    __syncthreads();
    short8 a0 = load_s8(&As[qd * 512 + (wr * 32 + c16) * 8]);
    short8 a1 = load_s8(&As[qd * 512 + (wr * 32 + 16 + c16) * 8]);
    short8 b0 = load_s8(&Bs[qd * 512 + (wc * 32 + c16) * 8]);
    short8 b1 = load_s8(&Bs[qd * 512 + (wc * 32 + 16 + c16) * 8]);
    acc[0][0] = mfma16(a0, b0, acc[0][0]);
    acc[0][1] = mfma16(a0, b1, acc[0][1]);
    acc[1][0] = mfma16(a1, b0, acc[1][0]);
    acc[1][1] = mfma16(a1, b1, acc[1][1]);
  }
#pragma unroll
  for (int mi = 0; mi < 2; mi++)
#pragma unroll
    for (int ni = 0; ni < 2; ni++) {
      int col = n0 + wc * 32 + ni * 16 + c16;
      float bs = bo[col];
      int gr0 = m0 + wr * 32 + mi * 16 + qd * 4;
#pragma unroll
      for (int r = 0; r < 4; r++)
        out0[(size_t)(gr0 + r) * HS_ + col] = acc[mi][ni][r] + bs;
    }
}

// ---------------------------------------------------------------------------
// K6: out = LayerNorm(out0 + residual) * g + b   [unchanged]
__global__ __launch_bounds__(256) void k_ln(
    const float* __restrict__ out0, const float* __restrict__ resid,
    const float* __restrict__ g, const float* __restrict__ bb,
    float* __restrict__ out) {
  int row = blockIdx.x;
  int tid = threadIdx.x, wave = tid >> 6, lane = tid & 63;
  const floatx4* x4 = reinterpret_cast<const floatx4*>(out0 + (size_t)row * HS_);
  const floatx4* r4 = reinterpret_cast<const floatx4*>(resid + (size_t)row * HS_);
  floatx4 x = x4[tid] + r4[tid];
  float s = x[0] + x[1] + x[2] + x[3];
  float ss = x[0]*x[0] + x[1]*x[1] + x[2]*x[2] + x[3]*x[3];
  __shared__ float red[8];
#pragma unroll
  for (int off = 32; off > 0; off >>= 1) {
    s += __shfl_xor(s, off);
    ss += __shfl_xor(ss, off);
  }
  if (lane == 0) { red[wave] = s; red[wave + 4] = ss; }
  __syncthreads();
  s = red[0] + red[1] + red[2] + red[3];
  ss = red[4] + red[5] + red[6] + red[7];
  float mu = s * (1.f / 1024.f);
  float var = ss * (1.f / 1024.f) - mu * mu;
  float rs = rsqrtf(var + 1e-5f);
  int c = tid * 4;
  floatx4 gg = *reinterpret_cast<const floatx4*>(g + c);
  floatx4 bv = *reinterpret_cast<const floatx4*>(bb + c);
  floatx4 y = (x - mu) * rs * gg + bv;
  reinterpret_cast<floatx4*>(out + (size_t)row * HS_)[tid] = y;
}

// ---------------------------------------------------------------------------
extern "C" void kernel_launch(void* const* d_in, const int* in_sizes, int n_in,
                              void* d_out, int out_size, void* d_ws, size_t ws_size,
                              hipStream_t stream) {
  const float* q   = (const float*)d_in[0];
  const float* k   = (const float*)d_in[1];
  const float* v   = (const float*)d_in[2];
  const int*   rp  = (const int*)d_in[3];
  const float* Wq  = (const float*)d_in[4];
  const float* bq  = (const float*)d_in[5];
  const float* Wk  = (const float*)d_in[6];
  const float* bk  = (const float*)d_in[7];
  const float* Wv  = (const float*)d_in[8];
  const float* bv  = (const float*)d_in[9];
  const float* rke = (const float*)d_in[10];
  const float* rve = (const float*)d_in[11];
  const float* Wo  = (const float*)d_in[12];
  const float* bo  = (const float*)d_in[13];
  const float* lng = (const float*)d_in[14];
  const float* lnb = (const float*)d_in[15];

  float* out = (float*)d_out;                         // (B,S,HS) f32
  float* weights = out + (size_t)B_ * S_ * HS_;       // (B,H,S,S) f32

  // workspace layout (bytes) — offsets audited for non-overlap:
  //   qh      [ 0        ,  4194304)
  //   kh      [ 4194304  ,  8388608)
  //   vhT     [ 8388608  , 12582912)
  //   (free)  [12582912  , 16777216)
  //   rveB    [16777216  , 16908416)   V_*D_*2  = 131200
  //   rkeB    [16912384  , 17043584)   V_*D_*2  = 131200
  //   ctxf    [17043968  , 25432576)   8 MB f32 (B,S,HS)
  //   out0    [25432576  , 33821184)   8 MB
  //   xb      [33821184  , 46404096)   3*2M*2 = 12 MB
  //   wb      [46404096  , 54792704)   4*1M*2 = 8 MB
  char* ws = (char*)d_ws;
  short* qh      = (short*)(ws);
  short* kh      = (short*)(ws + 4194304);
  short* vhT     = (short*)(ws + 8388608);
  short* rveB    = (short*)(ws + 16777216);
  short* rkeB    = (short*)(ws + 16912384);
  float* ctxf    = (float*)(ws + 17043968);
  float* out0    = (float*)(ws + 25432576);
  short* xb      = (short*)(ws + 33821184);
  short* wb      = (short*)(ws + 46404096);
  short* wob     = wb + (size_t)3 * (1 << 20);

  k_prep    <<<dim3(513),        256, 0, stream>>>(rve, rke, rveB, rkeB);
  k_cvt     <<<dim3(1024, 1, 7), 256, 0, stream>>>(q, k, v, Wq, Wk, Wv, Wo, xb, wb);
  k_proj    <<<dim3(32, 16, 3),  256, 0, stream>>>(xb, wb, bq, bk, bv, qh, kh, vhT);
  k_score   <<<dim3(64, 32),     256, 0, stream>>>(qh, kh, rkeB, rp, vhT, weights, ctxf);
  k_relgemm <<<dim3(1024),       256, 0, stream>>>(weights, rp, rveB, ctxf);
  k_oproj   <<<dim3(32, 16),     256, 0, stream>>>(ctxf, wob, bo, out0);
  k_ln      <<<dim3(2048),       256, 0, stream>>>(out0, q, lng, lnb, out);
}

// Round 7
// 385.082 us; speedup vs baseline: 1.5883x; 1.0024x over previous
//
#include <hip/hip_runtime.h>
#include <hip/hip_bf16.h>
#include <stdint.h>

// Problem constants
#define B_   2
#define S_   1024
#define HS_  1024
#define H_   16
#define D_   64
#define V_   1025   // vocab = 2*512+1
#define VP_  1056   // vocab padded to multiple of 32
#define BH_  32     // B_*H_
#define PTS_ 1096   // k_score SH row stride (shorts): 548 dwords, %32==4 -> 2-way banks
#define RVS_ 66     // Rv tile row stride (shorts), k_relgemm

typedef __attribute__((ext_vector_type(8))) short  short8;
typedef __attribute__((ext_vector_type(4))) short  short4v;
typedef __attribute__((ext_vector_type(4))) float  floatx4;
typedef __attribute__((ext_vector_type(4))) int    intx4;
typedef __bf16 bf16x8 __attribute__((ext_vector_type(8)));

// f32 -> bf16 (RNE), bit pattern as short
__device__ inline short f2b(float f) {
  union { float f; uint32_t u; } c; c.f = f;
  uint32_t u = c.u;
  uint32_t r = (u + 0x7fffu + ((u >> 16) & 1u)) >> 16;
  return (short)r;
}
__device__ inline float b2f(short s) {
  union { uint32_t u; float f; } c; c.u = ((uint32_t)(uint16_t)s) << 16;
  return c.f;
}
// load 8 f32 (32B) and convert to bf16x8 (as short8)
__device__ inline short8 cvt8(const float* p) {
  const floatx4* p4 = reinterpret_cast<const floatx4*>(p);
  floatx4 x = p4[0], y = p4[1];
  short8 r;
  r[0]=f2b(x[0]); r[1]=f2b(x[1]); r[2]=f2b(x[2]); r[3]=f2b(x[3]);
  r[4]=f2b(y[0]); r[5]=f2b(y[1]); r[6]=f2b(y[2]); r[7]=f2b(y[3]);
  return r;
}
__device__ inline short8 load_s8(const short* p) {
  return *reinterpret_cast<const short8*>(p);
}
__device__ inline floatx4 mfma16(short8 a, short8 b, floatx4 c) {
  return __builtin_amdgcn_mfma_f32_16x16x32_bf16(
      __builtin_bit_cast(bf16x8, a), __builtin_bit_cast(bf16x8, b), c, 0, 0, 0);
}

// ---------------------------------------------------------------------------
// K0: bulk f32->bf16 conversion of all bf16 operands:
//   z=0..2: q,k,v -> xb[z]  (2048x1024 each)
//   z=3..6: Wq,Wk,Wv,Wo -> wb[z-3]  (1024x1024 each)
//   z=7: rve -> rveB ; z=8: rke -> rkeB  (V_*D_ each)
__global__ __launch_bounds__(256) void k_cvt(
    const float* __restrict__ q, const float* __restrict__ k, const float* __restrict__ v,
    const float* __restrict__ Wq, const float* __restrict__ Wk,
    const float* __restrict__ Wv, const float* __restrict__ Wo,
    const float* __restrict__ rve, const float* __restrict__ rke,
    short* __restrict__ xb, short* __restrict__ wb,
    short* __restrict__ rveB, short* __restrict__ rkeB) {
  int z = blockIdx.z;
  const float* src = z == 0 ? q : z == 1 ? k : z == 2 ? v
                   : z == 3 ? Wq : z == 4 ? Wk : z == 5 ? Wv : z == 6 ? Wo
                   : z == 7 ? rve : rke;
  int n = (z < 3) ? (1 << 21) : (z < 7) ? (1 << 20) : (V_ * D_);
  short* dst = (z < 3) ? xb + (size_t)z * (1 << 21)
             : (z < 7) ? wb + (size_t)(z - 3) * (1 << 20)
             : (z == 7) ? rveB : rkeB;
  int i = (blockIdx.x * 256 + threadIdx.x) * 8;
  if (i < n) *reinterpret_cast<short8*>(&dst[i]) = cvt8(src + i);
}

// ---------------------------------------------------------------------------
// K1: projections from pre-converted bf16 inputs.
__global__ __launch_bounds__(256, 6) void k_proj(
    const short* __restrict__ xb, const short* __restrict__ wb,
    const float* __restrict__ bq, const float* __restrict__ bk, const float* __restrict__ bv,
    short* __restrict__ qh, short* __restrict__ kh, short* __restrict__ vhT) {
  int which = blockIdx.z;
  const short* A  = xb + (size_t)which * (2048u * 1024u);
  const short* Bm = wb + (size_t)which * (1024u * 1024u);
  const float* bias = which == 0 ? bq : which == 1 ? bk : bv;
  int m0 = blockIdx.x * 64, n0 = blockIdx.y * 64;
  int tid = threadIdx.x, wid = tid >> 6, lane = tid & 63;
  int wr = wid >> 1, wc = wid & 1, qd = lane >> 4, c16 = lane & 15;
  __shared__ short As[4 * 64 * 8];
  __shared__ short Bs[4 * 64 * 8];
  int kk = tid & 3, rowi = tid >> 2;
  const short* ga = A  + (size_t)(m0 + rowi) * HS_ + kk * 8;
  const short* gb = Bm + (size_t)(n0 + rowi) * HS_ + kk * 8;
  floatx4 acc[2][2] = {};
  for (int k0 = 0; k0 < HS_; k0 += 32) {
    short8 av = load_s8(ga + k0);
    short8 bv8 = load_s8(gb + k0);
    __syncthreads();
    *reinterpret_cast<short8*>(&As[kk * 512 + rowi * 8]) = av;
    *reinterpret_cast<short8*>(&Bs[kk * 512 + rowi * 8]) = bv8;
    __syncthreads();
    short8 a0 = load_s8(&As[qd * 512 + (wr * 32 + c16) * 8]);
    short8 a1 = load_s8(&As[qd * 512 + (wr * 32 + 16 + c16) * 8]);
    short8 b0 = load_s8(&Bs[qd * 512 + (wc * 32 + c16) * 8]);
    short8 b1 = load_s8(&Bs[qd * 512 + (wc * 32 + 16 + c16) * 8]);
    acc[0][0] = mfma16(a0, b0, acc[0][0]);
    acc[0][1] = mfma16(a0, b1, acc[0][1]);
    acc[1][0] = mfma16(a1, b0, acc[1][0]);
    acc[1][1] = mfma16(a1, b1, acc[1][1]);
  }
#pragma unroll
  for (int mi = 0; mi < 2; mi++)
#pragma unroll
    for (int ni = 0; ni < 2; ni++) {
      int col = n0 + wc * 32 + ni * 16 + c16;
      float bs = bias[col];
      int gr0 = m0 + wr * 32 + mi * 16 + qd * 4;
      if (which < 2) {
        short* dst = which == 0 ? qh : kh;
#pragma unroll
        for (int r = 0; r < 4; r++)
          dst[(size_t)(gr0 + r) * HS_ + col] = f2b(acc[mi][ni][r] + bs);
      } else {
        int h = col >> 6, d = col & 63;
        int bb = gr0 >> 10, s = gr0 & 1023;
        short4v pk;
#pragma unroll
        for (int r = 0; r < 4; r++) pk[r] = f2b(acc[mi][ni][r] + bs);
        *reinterpret_cast<short4v*>(&vhT[(((size_t)(bb * H_ + h)) * D_ + d) * S_ + s]) = pk;
      }
    }
}

// ---------------------------------------------------------------------------
// K3a: scores + fused PV for one (b,h, 16-q tile). [unchanged from round 6]
__global__ __launch_bounds__(256, 4) void k_score(
    const short* __restrict__ qh, const short* __restrict__ kh,
    const short* __restrict__ rkeB, const int* __restrict__ rp,
    const short* __restrict__ vhT, float* __restrict__ weights,
    float* __restrict__ ctxf) {
  int bh = blockIdx.y;
  int b = bh >> 4, h = bh & 15;
  int q0 = blockIdx.x * 16;
  int tid = threadIdx.x, wave = tid >> 6, lane = tid & 63;
  int qd = lane >> 4, c16 = lane & 15;
  __shared__ short SH[16 * PTS_];    // Rt (P0-P1), then P (P3-P4)
  __shared__ float redA[4 * 16];
  __shared__ float redB[4 * 16];

  const short* aptr = qh + ((size_t)b * S_ + q0 + c16) * HS_ + h * 64 + qd * 8;
  short8 a0 = load_s8(aptr), a1 = load_s8(aptr + 32);

  // ---- P0: Rt
  for (int nt = wave; nt < VP_ / 16; nt += 4) {
    int p = nt * 16 + c16;
    short8 b0 = {}, b1 = {};
    if (p < V_) {
      b0 = load_s8(rkeB + (size_t)p * D_ + qd * 8);
      b1 = load_s8(rkeB + (size_t)p * D_ + 32 + qd * 8);
    }
    floatx4 acc = {};
    acc = mfma16(a0, b0, acc);
    acc = mfma16(a1, b1, acc);
#pragma unroll
    for (int r = 0; r < 4; r++) SH[(qd * 4 + r) * PTS_ + p] = f2b(acc[r]);
  }
  __syncthreads();

  // ---- P1: logits
  floatx4 acc[16];
  const int* rpq = rp + (size_t)q0 * S_;
#pragma unroll
  for (int it = 0; it < 16; it++) {
    int col = wave * 256 + it * 16 + c16;
    const short* bptr = kh + ((size_t)b * S_ + col) * HS_ + h * 64 + qd * 8;
    floatx4 a = {};
    a = mfma16(a0, load_s8(bptr), a);
    a = mfma16(a1, load_s8(bptr + 32), a);
#pragma unroll
    for (int r = 0; r < 4; r++) {
      int row = qd * 4 + r;
      int p = rpq[(size_t)row * S_ + col];
      a[r] += b2f(SH[row * PTS_ + p]);
    }
    acc[it] = a;
  }

  // ---- P2: softmax
  float mx[4], inv[4];
#pragma unroll
  for (int r = 0; r < 4; r++) {
    float m = -1e30f;
#pragma unroll
    for (int it = 0; it < 16; it++) m = fmaxf(m, acc[it][r]);
#pragma unroll
    for (int off = 1; off < 16; off <<= 1) m = fmaxf(m, __shfl_xor(m, off));
    mx[r] = m;
    if (c16 == 0) redA[wave * 16 + qd * 4 + r] = m;
  }
  __syncthreads();
#pragma unroll
  for (int r = 0; r < 4; r++) {
    int row = qd * 4 + r;
    float m = fmaxf(fmaxf(redA[row], redA[16 + row]),
                    fmaxf(redA[32 + row], redA[48 + row]));
    mx[r] = m;
  }
  float sm[4] = {0.f, 0.f, 0.f, 0.f};
#pragma unroll
  for (int it = 0; it < 16; it++) {
#pragma unroll
    for (int r = 0; r < 4; r++) {
      float e = __expf(acc[it][r] - mx[r]);
      acc[it][r] = e;
      sm[r] += e;
    }
  }
#pragma unroll
  for (int r = 0; r < 4; r++) {
#pragma unroll
    for (int off = 1; off < 16; off <<= 1) sm[r] += __shfl_xor(sm[r], off);
    if (c16 == 0) redB[wave * 16 + qd * 4 + r] = sm[r];
  }
  __syncthreads();
#pragma unroll
  for (int r = 0; r < 4; r++) {
    int row = qd * 4 + r;
    inv[r] = 1.f / (redB[row] + redB[16 + row] + redB[32 + row] + redB[48 + row]);
  }

  // ---- P3: write weights (global) + P (LDS, overwrites Rt region)
  float* wout = weights + (size_t)bh * S_ * S_ + (size_t)q0 * S_;
#pragma unroll
  for (int it = 0; it < 16; it++) {
    int col = wave * 256 + it * 16 + c16;
#pragma unroll
    for (int r = 0; r < 4; r++) {
      int row = qd * 4 + r;
      float w = acc[it][r] * inv[r];
      wout[(size_t)row * S_ + col] = w;
      SH[row * PTS_ + col] = f2b(w);
    }
  }
  __syncthreads();

  // ---- P4: ctxf = P @ vhT (per wave: 16 q x 16 d, K=1024)
  {
    int d0 = wave * 16;
    const short* vb = vhT + ((size_t)bh * D_ + d0 + c16) * S_ + qd * 8;
    floatx4 apv = {};
    for (int kc = 0; kc < S_; kc += 32) {
      short8 pa = load_s8(&SH[c16 * PTS_ + kc + qd * 8]);
      apv = mfma16(pa, load_s8(vb + kc), apv);
    }
    float* cf = ctxf + ((size_t)b * S_ + q0 + qd * 4) * HS_ + h * 64 + d0 + c16;
#pragma unroll
    for (int r = 0; r < 4; r++) cf[(size_t)r * HS_] = apv[r];
  }
}

// ---------------------------------------------------------------------------
// K3b: relative-value context as a per-q GEMM; accumulates += into ctxf
//   (8 blocks/CU: LDS ~11 KB, VGPR ~52)
__global__ __launch_bounds__(256, 8) void k_relgemm(
    const float* __restrict__ weights, const int* __restrict__ rp,
    const short* __restrict__ rveB, float* __restrict__ ctxf) {
  int q = blockIdx.x;
  int tid = threadIdx.x, wave = tid >> 6, lane = tid & 63;
  int qd = lane >> 4, c16 = lane & 15;
  __shared__ int   rpl[S_];
  __shared__ short Wl[32][40];
  __shared__ short Rv[32][RVS_];

  {
    const intx4* r4 = reinterpret_cast<const intx4*>(rp + (size_t)q * S_);
    reinterpret_cast<intx4*>(rpl)[tid] = r4[tid];
  }
  __syncthreads();

  int sn = tid >> 3;
  int part = tid & 7;
  const float* wbase = weights + ((size_t)sn * S_ + q) * S_;
  floatx4 acc0 = {}, acc1 = {};
  int d0 = wave * 16;

  for (int kc = 0; kc < S_; kc += 32) {
    {
      int skA = (tid & 7) * 4;
      floatx4 wv = *reinterpret_cast<const floatx4*>(wbase + kc + skA);
      short4v pk;
      pk[0] = f2b(wv[0]); pk[1] = f2b(wv[1]);
      pk[2] = f2b(wv[2]); pk[3] = f2b(wv[3]);
      *reinterpret_cast<short4v*>(&Wl[sn][skA]) = pk;
    }
    {
      int p = rpl[kc + sn];
      *reinterpret_cast<short8*>(&Rv[sn][part * 8]) =
          load_s8(rveB + (size_t)p * D_ + part * 8);
    }
    __syncthreads();
    short8 a0 = *reinterpret_cast<const short8*>(&Wl[c16][qd * 8]);
    short8 a1 = *reinterpret_cast<const short8*>(&Wl[16 + c16][qd * 8]);
    short8 bfr;
#pragma unroll
    for (int j = 0; j < 8; j++) bfr[j] = Rv[qd * 8 + j][d0 + c16];
    acc0 = mfma16(a0, bfr, acc0);
    acc1 = mfma16(a1, bfr, acc1);
    __syncthreads();
  }

  int dd = d0 + c16;
#pragma unroll
  for (int r = 0; r < 4; r++) {
    int bh0 = qd * 4 + r;
    size_t o0 = ((size_t)0 * S_ + q) * HS_ + bh0 * 64 + dd;
    size_t o1 = ((size_t)1 * S_ + q) * HS_ + bh0 * 64 + dd;
    ctxf[o0] += acc0[r];
    ctxf[o1] += acc1[r];
  }
}

// ---------------------------------------------------------------------------
// K5: out0 = ctxf @ Wo^T + bo   (f32 A with cvt-in-stage, bf16 B)
__global__ __launch_bounds__(256, 6) void k_oproj(
    const float* __restrict__ ctxf, const short* __restrict__ wob,
    const float* __restrict__ bo, float* __restrict__ out0) {
  int m0 = blockIdx.x * 64, n0 = blockIdx.y * 64;
  int tid = threadIdx.x, wid = tid >> 6, lane = tid & 63;
  int wr = wid >> 1, wc = wid & 1, qd = lane >> 4, c16 = lane & 15;
  __shared__ short As[4 * 64 * 8];
  __shared__ short Bs[4 * 64 * 8];
  int kk = tid & 3, rowi = tid >> 2;
  const float* ga = ctxf + (size_t)(m0 + rowi) * HS_ + kk * 8;
  const short* gb = wob + (size_t)(n0 + rowi) * HS_ + kk * 8;
  floatx4 acc[2][2] = {};
  for (int k0 = 0; k0 < HS_; k0 += 32) {
    short8 av = cvt8(ga + k0);
    short8 bv8 = load_s8(gb + k0);
    __syncthreads();
    *reinterpret_cast<short8*>(&As[kk * 512 + rowi * 8]) = av;
    *reinterpret_cast<short8*>(&Bs[kk * 512 + rowi * 8]) = bv8;
    __syncthreads();
    short8 a0 = load_s8(&As[qd * 512 + (wr * 32 + c16) * 8]);
    short8 a1 = load_s8(&As[qd * 512 + (wr * 32 + 16 + c16) * 8]);
    short8 b0 = load_s8(&Bs[qd * 512 + (wc * 32 + c16) * 8]);
    short8 b1 = load_s8(&Bs[qd * 512 + (wc * 32 + 16 + c16) * 8]);
    acc[0][0] = mfma16(a0, b0, acc[0][0]);
    acc[0][1] = mfma16(a0, b1, acc[0][1]);
    acc[1][0] = mfma16(a1, b0, acc[1][0]);
    acc[1][1] = mfma16(a1, b1, acc[1][1]);
  }
#pragma unroll
  for (int mi = 0; mi < 2; mi++)
#pragma unroll
    for (int ni = 0; ni < 2; ni++) {
      int col = n0 + wc * 32 + ni * 16 + c16;
      float bs = bo[col];
      int gr0 = m0 + wr * 32 + mi * 16 + qd * 4;
#pragma unroll
      for (int r = 0; r < 4; r++)
        out0[(size_t)(gr0 + r) * HS_ + col] = acc[mi][ni][r] + bs;
    }
}

// ---------------------------------------------------------------------------
// K6: out = LayerNorm(out0 + residual) * g + b   [unchanged]
__global__ __launch_bounds__(256) void k_ln(
    const float* __restrict__ out0, const float* __restrict__ resid,
    const float* __restrict__ g, const float* __restrict__ bb,
    float* __restrict__ out) {
  int row = blockIdx.x;
  int tid = threadIdx.x, wave = tid >> 6, lane = tid & 63;
  const floatx4* x4 = reinterpret_cast<const floatx4*>(out0 + (size_t)row * HS_);
  const floatx4* r4 = reinterpret_cast<const floatx4*>(resid + (size_t)row * HS_);
  floatx4 x = x4[tid] + r4[tid];
  float s = x[0] + x[1] + x[2] + x[3];
  float ss = x[0]*x[0] + x[1]*x[1] + x[2]*x[2] + x[3]*x[3];
  __shared__ float red[8];
#pragma unroll
  for (int off = 32; off > 0; off >>= 1) {
    s += __shfl_xor(s, off);
    ss += __shfl_xor(ss, off);
  }
  if (lane == 0) { red[wave] = s; red[wave + 4] = ss; }
  __syncthreads();
  s = red[0] + red[1] + red[2] + red[3];
  ss = red[4] + red[5] + red[6] + red[7];
  float mu = s * (1.f / 1024.f);
  float var = ss * (1.f / 1024.f) - mu * mu;
  float rs = rsqrtf(var + 1e-5f);
  int c = tid * 4;
  floatx4 gg = *reinterpret_cast<const floatx4*>(g + c);
  floatx4 bv = *reinterpret_cast<const floatx4*>(bb + c);
  floatx4 y = (x - mu) * rs * gg + bv;
  reinterpret_cast<floatx4*>(out + (size_t)row * HS_)[tid] = y;
}

// ---------------------------------------------------------------------------
extern "C" void kernel_launch(void* const* d_in, const int* in_sizes, int n_in,
                              void* d_out, int out_size, void* d_ws, size_t ws_size,
                              hipStream_t stream) {
  const float* q   = (const float*)d_in[0];
  const float* k   = (const float*)d_in[1];
  const float* v   = (const float*)d_in[2];
  const int*   rp  = (const int*)d_in[3];
  const float* Wq  = (const float*)d_in[4];
  const float* bq  = (const float*)d_in[5];
  const float* Wk  = (const float*)d_in[6];
  const float* bk  = (const float*)d_in[7];
  const float* Wv  = (const float*)d_in[8];
  const float* bv  = (const float*)d_in[9];
  const float* rke = (const float*)d_in[10];
  const float* rve = (const float*)d_in[11];
  const float* Wo  = (const float*)d_in[12];
  const float* bo  = (const float*)d_in[13];
  const float* lng = (const float*)d_in[14];
  const float* lnb = (const float*)d_in[15];

  float* out = (float*)d_out;                         // (B,S,HS) f32
  float* weights = out + (size_t)B_ * S_ * HS_;       // (B,H,S,S) f32

  // workspace layout (bytes) — offsets audited for non-overlap:
  //   qh      [ 0        ,  4194304)
  //   kh      [ 4194304  ,  8388608)
  //   vhT     [ 8388608  , 12582912)
  //   (free)  [12582912  , 16777216)
  //   rveB    [16777216  , 16908416)   V_*D_*2  = 131200
  //   rkeB    [16912384  , 17043584)   V_*D_*2  = 131200
  //   ctxf    [17043968  , 25432576)   8 MB f32 (B,S,HS)
  //   out0    [25432576  , 33821184)   8 MB
  //   xb      [33821184  , 46404096)   3*2M*2 = 12 MB
  //   wb      [46404096  , 54792704)   4*1M*2 = 8 MB
  char* ws = (char*)d_ws;
  short* qh      = (short*)(ws);
  short* kh      = (short*)(ws + 4194304);
  short* vhT     = (short*)(ws + 8388608);
  short* rveB    = (short*)(ws + 16777216);
  short* rkeB    = (short*)(ws + 16912384);
  float* ctxf    = (float*)(ws + 17043968);
  float* out0    = (float*)(ws + 25432576);
  short* xb      = (short*)(ws + 33821184);
  short* wb      = (short*)(ws + 46404096);
  short* wob     = wb + (size_t)3 * (1 << 20);

  k_cvt     <<<dim3(1024, 1, 9), 256, 0, stream>>>(q, k, v, Wq, Wk, Wv, Wo, rve, rke,
                                                   xb, wb, rveB, rkeB);
  k_proj    <<<dim3(32, 16, 3),  256, 0, stream>>>(xb, wb, bq, bk, bv, qh, kh, vhT);
  k_score   <<<dim3(64, 32),     256, 0, stream>>>(qh, kh, rkeB, rp, vhT, weights, ctxf);
  k_relgemm <<<dim3(1024),       256, 0, stream>>>(weights, rp, rveB, ctxf);
  k_oproj   <<<dim3(32, 16),     256, 0, stream>>>(ctxf, wob, bo, out0);
  k_ln      <<<dim3(2048),       256, 0, stream>>>(out0, q, lng, lnb, out);
}